// Round 1
// 527.165 us; speedup vs baseline: 1.0594x; 1.0594x over previous
//
#include <hip/hip_runtime.h>
#include <stdint.h>

typedef unsigned short u16;
typedef _Float16 v8h __attribute__((ext_vector_type(8)));
typedef float v4f __attribute__((ext_vector_type(4)));

static __device__ __forceinline__ float h2f(u16 u) {
    union { u16 s; _Float16 h; } v; v.s = u; return (float)v.h;
}
static __device__ __forceinline__ u16 f2h(float f) {
    union { u16 s; _Float16 h; } v; v.h = (_Float16)f; return v.s;
}

// async global->LDS, 16B per lane. lds dest = wave-uniform base + lane*16.
static __device__ __forceinline__ void gload_lds16(const u16* g, const u16* l) {
    __builtin_amdgcn_global_load_lds(
        (const __attribute__((address_space(1))) uint32_t*)(uintptr_t)g,
        (__attribute__((address_space(3))) uint32_t*)(uintptr_t)l,
        16, 0, 0);
}

// ---------------- convert f32 -> f16, vectorized x8 ----------------
__global__ __launch_bounds__(256) void cvt_f16(const float* __restrict__ in,
                                               u16* __restrict__ out, int n8) {
    const int i = blockIdx.x * 256 + threadIdx.x;
    if (i >= n8) return;
    const float4 a = ((const float4*)in)[2 * i];
    const float4 b = ((const float4*)in)[2 * i + 1];
    u16 o[8] = {f2h(a.x), f2h(a.y), f2h(a.z), f2h(a.w),
                f2h(b.x), f2h(b.y), f2h(b.z), f2h(b.w)};
    *(uint4*)(out + (size_t)i * 8) = *(const uint4*)o;
}

// ---------------- all weight transposes f32 [R][C] -> f16 [C][R], one launch ----------------
__global__ __launch_bounds__(256) void transpose_all(
    const float* __restrict__ Wq, const float* __restrict__ Wk,
    const float* __restrict__ Wv, const float* __restrict__ Wo,
    const float* __restrict__ W1, const float* __restrict__ W2,
    u16* __restrict__ WqkvT, u16* __restrict__ WoT,
    u16* __restrict__ W1T, u16* __restrict__ W2T)
{
    int t = blockIdx.x;
    const float* in; u16* out; long ldi, ldo; int xt;
    if (t < 1024)      {            in = Wq; out = WqkvT;               ldi = 1024; ldo = 1024; xt = 32; }
    else if (t < 2048) { t -= 1024; in = Wk; out = WqkvT + 1024*1024;   ldi = 1024; ldo = 1024; xt = 32; }
    else if (t < 3072) { t -= 2048; in = Wv; out = WqkvT + 2*1024*1024; ldi = 1024; ldo = 1024; xt = 32; }
    else if (t < 4096) { t -= 3072; in = Wo; out = WoT;                 ldi = 1024; ldo = 1024; xt = 32; }
    else if (t < 8192) { t -= 4096; in = W1; out = W1T;                 ldi = 4096; ldo = 1024; xt = 128; }
    else               { t -= 8192; in = W2; out = W2T;                 ldi = 1024; ldo = 4096; xt = 32; }
    const int c0 = (t % xt) * 32, r0 = (t / xt) * 32;
    __shared__ float tile[32][33];
    for (int i = threadIdx.y; i < 32; i += 8)
        tile[i][threadIdx.x] = in[(long)(r0 + i) * ldi + c0 + threadIdx.x];
    __syncthreads();
    for (int i = threadIdx.y; i < 32; i += 8)
        out[(long)(c0 + i) * ldo + r0 + threadIdx.x] = f2h(tile[threadIdx.x][i]);
}

// ======== legacy 128x128 f16 GEMM: C = A @ B^T (+bias)(+relu) ========
// Kept for the N=1024 GEMMs (PV, Wo, FF2) where a 256-wide tile would only
// fill half the device. BK=64, XOR-swizzled LDS, drain-style barriers.
template<int OMODE, int BIAS, bool RELU, int NX, int NY, int NZ>
__global__ __launch_bounds__(256) void gemm_f16(
    const u16* __restrict__ A, long lda, long Asb,
    const u16* __restrict__ B, long ldb, long Bsb,
    void* __restrict__ Cv, long ldc, long Csb, u16* __restrict__ C1,
    const float* __restrict__ bias, const float* __restrict__ bias2,
    const float* __restrict__ bias3, int K)
{
    static_assert((NY * NZ) % 8 == 0, "Y-band remap needs NY*NZ % 8 == 0");
    alignas(16) __shared__ u16 As[128 * 64];
    alignas(16) __shared__ u16 Bs[128 * 64];
    const int t = threadIdx.x;

    const int lin = blockIdx.x + NX * (blockIdx.y + NY * blockIdx.z);
    const int g = lin & 7;
    const int s = lin >> 3;
    const int xe = s % NX;
    const int yl = s / NX;
    const int Y = g * (NY * NZ / 8) + yl;
    const int ye = Y % NY;
    const long b = Y / NY;

    A += b * Asb; B += b * Bsb;
    const long m0 = (long)ye * 128;
    const long n0 = (long)xe * 128;
    const int lane = t & 63, wave = t >> 6;
    const int wm = (wave >> 1) * 64, wn = (wave & 1) * 64;
    const int l16 = lane & 15, quad = lane >> 4;

    const int rr = t >> 3;
    const int cg8 = ((t & 7) ^ ((t >> 3) & 7)) * 8;
    const int wv512 = wave * 512;

    long aofs[4], bofs[4];
#pragma unroll
    for (int p = 0; p < 4; ++p) {
        aofs[p] = (m0 + p * 32 + rr) * lda + cg8;
        bofs[p] = (n0 + p * 32 + rr) * ldb + cg8;
    }

    v4f acc[4][4];
#pragma unroll
    for (int i = 0; i < 4; ++i)
#pragma unroll
        for (int j = 0; j < 4; ++j)
            acc[i][j] = (v4f){0.f, 0.f, 0.f, 0.f};

    for (int k0 = 0; k0 < K; k0 += 64) {
        __syncthreads();
#pragma unroll
        for (int p = 0; p < 4; ++p) {
            gload_lds16(A + aofs[p] + k0, As + p * 2048 + wv512);
            gload_lds16(B + bofs[p] + k0, Bs + p * 2048 + wv512);
        }
        __syncthreads();

#pragma unroll
        for (int kk = 0; kk < 2; ++kk) {
            const int swz = ((kk * 4 + quad) ^ (l16 & 7)) * 8;
            v8h af[4], bfr[4];
#pragma unroll
            for (int i = 0; i < 4; ++i)
                af[i] = *(const v8h*)&As[(wm + i * 16 + l16) * 64 + swz];
#pragma unroll
            for (int j = 0; j < 4; ++j)
                bfr[j] = *(const v8h*)&Bs[(wn + j * 16 + l16) * 64 + swz];
#pragma unroll
            for (int i = 0; i < 4; ++i)
#pragma unroll
                for (int j = 0; j < 4; ++j)
                    acc[i][j] = __builtin_amdgcn_mfma_f32_16x16x32_f16(af[i], bfr[j], acc[i][j], 0, 0, 0);
        }
    }

    float bv[4];
#pragma unroll
    for (int j = 0; j < 4; ++j) {
        const long col = n0 + wn + j * 16 + l16;
        if (BIAS == 0) bv[j] = 0.f;
        else if (BIAS == 1) bv[j] = bias[col];
        else {
            const int sel = (int)(col >> 10);
            const float* bp = sel == 0 ? bias : (sel == 1 ? bias2 : bias3);
            bv[j] = bp[col & 1023];
        }
    }

    if (OMODE == 3 && n0 >= 2048) {
        const long bb = m0 >> 11, mb = m0 & 2047;
        u16* C = C1 + bb * Csb;
#pragma unroll
        for (int j = 0; j < 4; ++j) {
            const long col = n0 - 2048 + wn + j * 16 + l16;
            u16* pc = C + col * 2048 + mb + wm + quad * 4;
#pragma unroll
            for (int i = 0; i < 4; ++i) {
                u16 o[4];
#pragma unroll
                for (int r = 0; r < 4; ++r) {
                    float val = acc[i][j][r] + bv[j];
                    if (RELU) val = fmaxf(val, 0.f);
                    o[r] = f2h(val);
                }
                *(uint2*)(pc + i * 16) = *(const uint2*)o;
            }
        }
    } else {
        const long cb = b * ((OMODE == 3) ? 0 : Csb) + (m0 + wm + quad * 4) * ldc + (n0 + wn + l16);
        u16* p0 = (u16*)Cv + cb;
#pragma unroll
        for (int i = 0; i < 4; ++i)
#pragma unroll
            for (int r = 0; r < 4; ++r) {
                u16* prow = p0 + (long)(i * 16 + r) * ldc;
#pragma unroll
                for (int j = 0; j < 4; ++j) {
                    float val = acc[i][j][r] + bv[j];
                    if (RELU) val = fmaxf(val, 0.f);
                    prow[j * 16] = f2h(val);
                }
            }
    }
}

// ======== 256x256 8-phase f16 GEMM: C = A @ B^T (+bias)(+relu) ========
// T2+T3+T4+T5 port of the verified 8-phase template (plain HIP):
//  - 512 thr / 8 waves (2M x 4N), per-wave 128x64 output, BK=64.
//  - LDS 128 KiB: per operand 2 K-tile buffers x 2 k-half regions
//    (region = [256 rows][32 k] f16 = 16 KiB).
//  - 8 phases per loop iteration (2 K-tiles). Phase = {ds_read frags,
//    stage 1 region via global_load_lds, s_barrier, lgkmcnt(0),
//    setprio(1) + 16 MFMA + setprio(0), s_barrier}.
//  - Region overwritten exactly one phase after its last read; stage
//    stream runs 3 regions (6 loads) ahead -> s_waitcnt vmcnt(6) at even
//    phases only; never vmcnt(0) in the main loop (raw s_barrier, no
//    __syncthreads => no implicit drain).
//  - LDS swizzle: 16B slot' = q ^ ((row>>1)&3) within each 64B row
//    (2 lanes/bank on ds_read_b128 = conflict-free). Applied on BOTH
//    sides: inverse-permuted global source in the stage + same XOR on read.
// MFMA k-order identical to gemm_f16 -> bit-identical accumulation.
template<int OMODE, int BIAS, bool RELU, int NX, int NY, int NZ>
__global__ __launch_bounds__(512) void gemm256(
    const u16* __restrict__ A, long lda, long Asb,
    const u16* __restrict__ B, long ldb, long Bsb,
    void* __restrict__ Cv, long ldc, long Csb, u16* __restrict__ C1,
    const float* __restrict__ bias, const float* __restrict__ bias2,
    const float* __restrict__ bias3, int K)
{
    constexpr int NWG = NX * NY * NZ;
    static_assert(NWG % 8 == 0, "XCD swizzle needs nwg % 8 == 0");
    // 4 regions per operand: idx = buf*2 + kh, each 8192 u16 (16 KiB)
    alignas(16) __shared__ u16 As[4 * 8192];
    alignas(16) __shared__ u16 Bs[4 * 8192];

    const int tid = threadIdx.x;           // 0..511
    const int lane = tid & 63, wave = tid >> 6;
    const int l16 = lane & 15, quad = lane >> 4;
    const int wm = wave >> 2;              // 0..1  (M)
    const int wn = wave & 3;               // 0..3  (N)

    // ---- XCD swizzle (bijective: NWG % 8 == 0) ----
    const int lin = blockIdx.x;
    const int tl = (lin & 7) * (NWG / 8) + (lin >> 3);
    const int xe = tl % NX;
    const int ye = (tl / NX) % NY;
    const int zb = tl / (NX * NY);
    const long m0 = (long)ye * 256;
    const long n0 = (long)xe * 256;

    const u16* Aop = A + (long)zb * Asb;
    const u16* Bop = B + (long)zb * Bsb;

    // ---- stage addressing: slot s in [0,1024), rows 0..255, 4 slots/row.
    // content of slot s = global k-group q = (s&3) ^ ((s>>3)&3)   (inverse swz)
    const int srow = tid >> 2;
    const int sq = (tid & 3) ^ ((tid >> 3) & 3);
    const long gaofs0 = (m0 + srow) * lda + sq * 8;
    const long gaofs1 = gaofs0 + 128 * lda;
    const long gbofs0 = (n0 + srow) * ldb + sq * 8;
    const long gbofs1 = gbofs0 + 128 * ldb;
    const int wv512n = wave * 512;         // wave-uniform LDS element base

    // ---- ds_read addressing (elements): region row stride 32, swizzled slot
    const int swzE = (quad ^ ((l16 >> 1) & 3)) * 8;
    const int aRow = (wm * 128 + l16) * 32 + swzE;
    const int bRow = (wn * 64 + l16) * 32 + swzE;

    v4f acc[8][4];
#pragma unroll
    for (int i = 0; i < 8; ++i)
#pragma unroll
        for (int j = 0; j < 4; ++j)
            acc[i][j] = (v4f){0.f, 0.f, 0.f, 0.f};
    v8h bf[4];

#define STAGE_A(RIDX, KP) do { \
        u16* lb_ = As + (RIDX) * 8192 + wv512n; \
        gload_lds16(Aop + gaofs0 + (KP), lb_); \
        gload_lds16(Aop + gaofs1 + (KP), lb_ + 4096); } while (0)
#define STAGE_B(RIDX, KP) do { \
        u16* lb_ = Bs + (RIDX) * 8192 + wv512n; \
        gload_lds16(Bop + gbofs0 + (KP), lb_); \
        gload_lds16(Bop + gbofs1 + (KP), lb_ + 4096); } while (0)

#define MF(CH, I, J) \
    acc[(CH) * 4 + (I)][J] = __builtin_amdgcn_mfma_f32_16x16x32_f16( \
        af##I, bf[J], acc[(CH) * 4 + (I)][J], 0, 0, 0)

#define PHASE(BUF, KH, CH, EVENW, ...) { \
        if (EVENW) asm volatile("s_waitcnt vmcnt(6)" ::: "memory"); \
        const u16* Ar_ = As + ((BUF) * 2 + (KH)) * 8192 + aRow + (CH) * 2048; \
        v8h af0 = *(const v8h*)(Ar_); \
        v8h af1 = *(const v8h*)(Ar_ + 512); \
        v8h af2 = *(const v8h*)(Ar_ + 1024); \
        v8h af3 = *(const v8h*)(Ar_ + 1536); \
        if ((CH) == 0) { \
            const u16* Br_ = Bs + ((BUF) * 2 + (KH)) * 8192 + bRow; \
            bf[0] = *(const v8h*)(Br_); \
            bf[1] = *(const v8h*)(Br_ + 512); \
            bf[2] = *(const v8h*)(Br_ + 1024); \
            bf[3] = *(const v8h*)(Br_ + 1536); \
        } \
        __VA_ARGS__; \
        __builtin_amdgcn_s_barrier(); \
        asm volatile("s_waitcnt lgkmcnt(0)" ::: "memory"); \
        __builtin_amdgcn_s_setprio(1); \
        MF(CH,0,0); MF(CH,0,1); MF(CH,0,2); MF(CH,0,3); \
        MF(CH,1,0); MF(CH,1,1); MF(CH,1,2); MF(CH,1,3); \
        MF(CH,2,0); MF(CH,2,1); MF(CH,2,2); MF(CH,2,3); \
        MF(CH,3,0); MF(CH,3,1); MF(CH,3,2); MF(CH,3,3); \
        __builtin_amdgcn_s_setprio(0); \
        __builtin_amdgcn_s_barrier(); \
    }

    // ---- prologue: tile0 -> buf0 (kh0,kh1), tile1.kh0 -> buf1 (12 loads) ----
    STAGE_A(0, 0);  STAGE_B(0, 0);
    STAGE_A(1, 32); STAGE_B(1, 32);
    STAGE_A(2, 64); STAGE_B(2, 64);
    asm volatile("s_waitcnt vmcnt(8)" ::: "memory");   // buf0.kh0 resident
    __builtin_amdgcn_s_barrier();

    const int NT = K >> 7;   // iterations of 2 K-tiles (K % 128 == 0)
#pragma unroll 1
    for (int t = 0; t < NT; ++t) {
        const bool nl = (t < NT - 1);
        const long kb = (long)t * 128;
        const long kp1 = kb + 96;    // tile 2t+1, kh1
        const long kp2 = kb + 128;   // tile 2t+2, kh0
        const long kp2b = kb + 160;  // tile 2t+2, kh1
        const long kp3 = kb + 192;   // tile 2t+3, kh0

        PHASE(0, 0, 0, false, STAGE_A(3, kp1))                  // P1
        PHASE(0, 0, 1, true,  STAGE_B(3, kp1))                  // P2
        PHASE(0, 1, 0, false, if (nl) STAGE_A(0, kp2))          // P3
        PHASE(0, 1, 1, true,  if (nl) STAGE_B(0, kp2))          // P4
        PHASE(1, 0, 0, false, if (nl) STAGE_A(1, kp2b))         // P5
        PHASE(1, 0, 1, true,  if (nl) STAGE_B(1, kp2b))         // P6
        PHASE(1, 1, 0, false, if (nl) STAGE_A(2, kp3))          // P7
        PHASE(1, 1, 1, true,  if (nl) STAGE_B(2, kp3))          // P8
    }

#undef PHASE
#undef MF
#undef STAGE_A
#undef STAGE_B

    // ---- epilogue ----
    float bv[4];
#pragma unroll
    for (int j = 0; j < 4; ++j) {
        const long col = n0 + wn * 64 + j * 16 + l16;
        if (BIAS == 0) bv[j] = 0.f;
        else if (BIAS == 1) bv[j] = bias[col];
        else {
            const int sel = (int)(col >> 10);
            const float* bp = sel == 0 ? bias : (sel == 1 ? bias2 : bias3);
            bv[j] = bp[col & 1023];
        }
    }

    if (OMODE == 3 && n0 >= 2048) {
        // transposed batched write: C1[b][col-2048][row], batch rows = 2048
        const long bb = m0 >> 11, mb = m0 & 2047;
        u16* C = C1 + bb * Csb;
#pragma unroll
        for (int j = 0; j < 4; ++j) {
            const long col = n0 - 2048 + wn * 64 + j * 16 + l16;
            u16* pc = C + col * 2048 + mb + wm * 128 + quad * 4;
#pragma unroll
            for (int i = 0; i < 8; ++i) {
                u16 o[4];
#pragma unroll
                for (int r = 0; r < 4; ++r) {
                    float val = acc[i][j][r] + bv[j];
                    if (RELU) val = fmaxf(val, 0.f);
                    o[r] = f2h(val);
                }
                *(uint2*)(pc + i * 16) = *(const uint2*)o;
            }
        }
    } else {
        const long cb = (OMODE == 3 ? 0 : (long)zb * Csb)
                      + (m0 + wm * 128 + quad * 4) * ldc + (n0 + wn * 64 + l16);
        u16* p0 = (u16*)Cv + cb;
#pragma unroll
        for (int i = 0; i < 8; ++i)
#pragma unroll
            for (int r = 0; r < 4; ++r) {
                u16* prow = p0 + (long)(i * 16 + r) * ldc;
#pragma unroll
                for (int j = 0; j < 4; ++j) {
                    float val = acc[i][j][r] + bv[j];
                    if (RELU) val = fmaxf(val, 0.f);
                    prow[j * 16] = f2h(val);
                }
            }
    }
}

// ---------------- softmax over f16 rows of 2048, in place ----------------
__global__ __launch_bounds__(256) void softmax_rows(u16* __restrict__ S) {
    const long row = blockIdx.x;
    u16* p = S + row * 2048;
    const int t = threadIdx.x;
    float v[8];
    float mx = -1e30f;
#pragma unroll
    for (int i = 0; i < 8; ++i) { v[i] = h2f(p[t + i * 256]); mx = fmaxf(mx, v[i]); }
    __shared__ float red[256];
    red[t] = mx; __syncthreads();
    for (int off = 128; off > 0; off >>= 1) {
        if (t < off) red[t] = fmaxf(red[t], red[t + off]);
        __syncthreads();
    }
    mx = red[0]; __syncthreads();
    float sum = 0.f;
#pragma unroll
    for (int i = 0; i < 8; ++i) { v[i] = __expf(v[i] - mx); sum += v[i]; }
    red[t] = sum; __syncthreads();
    for (int off = 128; off > 0; off >>= 1) {
        if (t < off) red[t] += red[t + off];
        __syncthreads();
    }
    const float inv = 1.f / red[0];
#pragma unroll
    for (int i = 0; i < 8; ++i) p[t + i * 256] = f2h(v[i] * inv);
}

// ---------------- ln1: xh_f16 = LN(src_f32 + attnO_f16) ----------------
__global__ __launch_bounds__(256) void ln_one(
    const float* __restrict__ a, const u16* __restrict__ bb,
    const float* __restrict__ g, const float* __restrict__ be,
    u16* __restrict__ out16)
{
    const long base = (long)blockIdx.x * 1024;
    const int t = threadIdx.x;
    float v[4]; float s = 0.f, ss = 0.f;
#pragma unroll
    for (int i = 0; i < 4; ++i) {
        const int c = t + i * 256;
        const float x = a[base + c] + h2f(bb[base + c]);
        v[i] = x; s += x; ss += x * x;
    }
    __shared__ float rs[256], rss[256];
    rs[t] = s; rss[t] = ss; __syncthreads();
    for (int off = 128; off > 0; off >>= 1) {
        if (t < off) { rs[t] += rs[t + off]; rss[t] += rss[t + off]; }
        __syncthreads();
    }
    const float mean = rs[0] * (1.f / 1024.f);
    const float var = rss[0] * (1.f / 1024.f) - mean * mean;
    const float rstd = rsqrtf(var + 1e-5f);
#pragma unroll
    for (int i = 0; i < 4; ++i) {
        const int c = t + i * 256;
        out16[base + c] = f2h((v[i] - mean) * rstd * g[c] + be[c]);
    }
}

// ---------------- ln2: out_f32 = LN(xh_f16 + ffO_f16) ----------------
__global__ __launch_bounds__(256) void ln_two(
    const u16* __restrict__ a, const u16* __restrict__ bb,
    const float* __restrict__ g, const float* __restrict__ be,
    float* __restrict__ out)
{
    const long base = (long)blockIdx.x * 1024;
    const int t = threadIdx.x;
    float v[4]; float s = 0.f, ss = 0.f;
#pragma unroll
    for (int i = 0; i < 4; ++i) {
        const int c = t + i * 256;
        const float x = h2f(a[base + c]) + h2f(bb[base + c]);
        v[i] = x; s += x; ss += x * x;
    }
    __shared__ float rs[256], rss[256];
    rs[t] = s; rss[t] = ss; __syncthreads();
    for (int off = 128; off > 0; off >>= 1) {
        if (t < off) { rs[t] += rs[t + off]; rss[t] += rss[t + off]; }
        __syncthreads();
    }
    const float mean = rs[0] * (1.f / 1024.f);
    const float var = rss[0] * (1.f / 1024.f) - mean * mean;
    const float rstd = rsqrtf(var + 1e-5f);
#pragma unroll
    for (int i = 0; i < 4; ++i) {
        const int c = t + i * 256;
        out[base + c] = (v[i] - mean) * rstd * g[c] + be[c];
    }
}

extern "C" void kernel_launch(void* const* d_in, const int* in_sizes, int n_in,
                              void* d_out, int out_size, void* d_ws, size_t ws_size,
                              hipStream_t stream) {
    (void)in_sizes; (void)n_in; (void)out_size; (void)ws_size;
    constexpr long S = 2048, E = 1024, F = 4096, M = 8192;

    const float* src = (const float*)d_in[0];
    const float* Wq  = (const float*)d_in[1];
    const float* bq  = (const float*)d_in[2];
    const float* Wk  = (const float*)d_in[3];
    const float* bk  = (const float*)d_in[4];
    const float* Wv  = (const float*)d_in[5];
    const float* bv  = (const float*)d_in[6];
    const float* Wo  = (const float*)d_in[7];
    const float* bo  = (const float*)d_in[8];
    const float* W1  = (const float*)d_in[9];
    const float* b1  = (const float*)d_in[10];
    const float* W2  = (const float*)d_in[11];
    const float* b2  = (const float*)d_in[12];
    const float* g1  = (const float*)d_in[13];
    const float* be1 = (const float*)d_in[14];
    const float* g2  = (const float*)d_in[15];
    const float* be2 = (const float*)d_in[16];

    char* ws = (char*)d_ws;
    size_t off = 0;
    auto take = [&](size_t bytes) {
        char* p = ws + off;
        off += (bytes + 255) & ~(size_t)255;
        return p;
    };
    const size_t MB16 = 16777216;  // f16 [8192][1024]
    u16*   srcH  = (u16*)take(MB16);
    u16*   WqkvT = (u16*)take(3 * E * E * 2);     // [3072][1024]: WqT | WkT | WvT
    u16*   WoT   = (u16*)take(E * E * 2);
    u16*   W1T   = (u16*)take(F * E * 2);         // [4096][1024]
    u16*   W2T   = (u16*)take(E * F * 2);         // [1024][4096]
    char*  B0    = take(2 * MB16);                // QK f16 [8192][2048]
    char*  B1    = take(MB16);                    // VT f16 [4][1024][2048]
    char*  B2    = take(4ull * S * S * 4);        // Sh f16 (32M) -> hf f16 [8192][4096] (64M)
    char*  B3    = take(MB16);                    // attn f16 -> xh f16
    char*  B4    = take(MB16);                    // attnO f16 -> ffO f16

    u16*   QK    = (u16*)B0;
    u16*   VT    = (u16*)B1;
    u16*   Sh    = (u16*)B2;
    u16*   hf    = (u16*)B2;
    u16*   attn  = (u16*)B3;
    u16*   xh    = (u16*)B3;
    u16*   attnO = (u16*)B4;
    u16*   ffO   = (u16*)B4;

    dim3 blk(256), blk5(512), tb(32, 8);

    // 1) convert src -> f16
    cvt_f16<<<dim3(M * E / 8 / 256), blk, 0, stream>>>(src, srcH, M * E / 8);

    // 2) all weight transposes in one launch
    transpose_all<<<dim3(12288), tb, 0, stream>>>(Wq, Wk, Wv, Wo, W1, W2,
                                                  WqkvT, WoT, W1T, W2T);

    // 3) merged Q|K|V projection (8-phase 256^2): QK [8192][2048] + VT[b][col][row]
    gemm256<3, 3, false, 12, 32, 1><<<dim3(12 * 32), blk5, 0, stream>>>(
        srcH, E, 0, WqkvT, E, 0, QK, 2 * E, E * S, VT, bq, bk, bv, E);

    // 4) scores[b] = Q[b] @ K[b]^T (8-phase 256^2, f16 out, ld 2048)
    gemm256<0, 0, false, 8, 8, 4><<<dim3(8 * 8 * 4), blk5, 0, stream>>>(
        QK, 2 * E, S * 2 * E, QK + E, 2 * E, S * 2 * E,
        Sh, S, S * S, nullptr, nullptr, nullptr, nullptr, E);

    // 5) softmax in place (f16)
    softmax_rows<<<dim3(M), blk, 0, stream>>>(Sh);

    // 6) attn[b] = P[b] @ V[b]  (N=1024 -> keep 128^2 kernel, full device)
    gemm_f16<0, 0, false, 8, 16, 4><<<dim3(8, 16, 4), blk, 0, stream>>>(
        Sh, S, S * S, VT, S, E * S,
        attn, E, S * E, nullptr, nullptr, nullptr, nullptr, S);

    // 7) attnO = attn @ Wo + bo (N=1024 -> 128^2 kernel)
    gemm_f16<0, 1, false, 8, 64, 1><<<dim3(8, 64, 1), blk, 0, stream>>>(
        attn, E, 0, WoT, E, 0, attnO, E, 0, nullptr, bo, nullptr, nullptr, E);

    // 8) xh = LN(src + attnO) (f16, over dead attn)
    ln_one<<<dim3(M), blk, 0, stream>>>(src, attnO, g1, be1, xh);

    // 9) hf = relu(xh @ W1 + b1) (8-phase 256^2, f16, over dead Sh/P)
    gemm256<0, 1, true, 16, 32, 1><<<dim3(16 * 32), blk5, 0, stream>>>(
        xh, E, 0, W1T, E, 0, hf, F, 0, nullptr, b1, nullptr, nullptr, E);

    // 10) ffO = hf @ W2 + b2 (N=1024 -> 128^2 kernel)
    gemm_f16<0, 1, false, 8, 64, 1><<<dim3(8, 64, 1), blk, 0, stream>>>(
        hf, F, 0, W2T, F, 0, ffO, E, 0, nullptr, b2, nullptr, nullptr, F);

    // 11) out = LN(xh + ffO) -> f32
    ln_two<<<dim3(M), blk, 0, stream>>>(xh, ffO, g2, be2, (float*)d_out);
}

// Round 2
// 508.565 us; speedup vs baseline: 1.0982x; 1.0366x over previous
//
#include <hip/hip_runtime.h>
#include <stdint.h>

typedef unsigned short u16;
typedef _Float16 v8h __attribute__((ext_vector_type(8)));
typedef float v4f __attribute__((ext_vector_type(4)));

static __device__ __forceinline__ float h2f(u16 u) {
    union { u16 s; _Float16 h; } v; v.s = u; return (float)v.h;
}
static __device__ __forceinline__ u16 f2h(float f) {
    union { u16 s; _Float16 h; } v; v.h = (_Float16)f; return v.s;
}

// async global->LDS, 16B per lane. lds dest = wave-uniform base + lane*16.
static __device__ __forceinline__ void gload_lds16(const u16* g, const u16* l) {
    __builtin_amdgcn_global_load_lds(
        (const __attribute__((address_space(1))) uint32_t*)(uintptr_t)g,
        (__attribute__((address_space(3))) uint32_t*)(uintptr_t)l,
        16, 0, 0);
}

// ---------------- convert f32 -> f16, vectorized x8 ----------------
__global__ __launch_bounds__(256) void cvt_f16(const float* __restrict__ in,
                                               u16* __restrict__ out, int n8) {
    const int i = blockIdx.x * 256 + threadIdx.x;
    if (i >= n8) return;
    const float4 a = ((const float4*)in)[2 * i];
    const float4 b = ((const float4*)in)[2 * i + 1];
    u16 o[8] = {f2h(a.x), f2h(a.y), f2h(a.z), f2h(a.w),
                f2h(b.x), f2h(b.y), f2h(b.z), f2h(b.w)};
    *(uint4*)(out + (size_t)i * 8) = *(const uint4*)o;
}

// ---------------- all weight transposes f32 [R][C] -> f16 [C][R], one launch ----------------
__global__ __launch_bounds__(256) void transpose_all(
    const float* __restrict__ Wq, const float* __restrict__ Wk,
    const float* __restrict__ Wv, const float* __restrict__ Wo,
    const float* __restrict__ W1, const float* __restrict__ W2,
    u16* __restrict__ WqkvT, u16* __restrict__ WoT,
    u16* __restrict__ W1T, u16* __restrict__ W2T)
{
    int t = blockIdx.x;
    const float* in; u16* out; long ldi, ldo; int xt;
    if (t < 1024)      {            in = Wq; out = WqkvT;               ldi = 1024; ldo = 1024; xt = 32; }
    else if (t < 2048) { t -= 1024; in = Wk; out = WqkvT + 1024*1024;   ldi = 1024; ldo = 1024; xt = 32; }
    else if (t < 3072) { t -= 2048; in = Wv; out = WqkvT + 2*1024*1024; ldi = 1024; ldo = 1024; xt = 32; }
    else if (t < 4096) { t -= 3072; in = Wo; out = WoT;                 ldi = 1024; ldo = 1024; xt = 32; }
    else if (t < 8192) { t -= 4096; in = W1; out = W1T;                 ldi = 4096; ldo = 1024; xt = 128; }
    else               { t -= 8192; in = W2; out = W2T;                 ldi = 1024; ldo = 4096; xt = 32; }
    const int c0 = (t % xt) * 32, r0 = (t / xt) * 32;
    __shared__ float tile[32][33];
    for (int i = threadIdx.y; i < 32; i += 8)
        tile[i][threadIdx.x] = in[(long)(r0 + i) * ldi + c0 + threadIdx.x];
    __syncthreads();
    for (int i = threadIdx.y; i < 32; i += 8)
        out[(long)(c0 + i) * ldo + r0 + threadIdx.x] = f2h(tile[threadIdx.x][i]);
}

// ======== 256x256 8-phase f16 GEMM: C = A @ B^T (+bias)(+relu) ========
// 512 thr / 8 waves (2M x 4N), per-wave 128x64 output, BK=64.
// LDS 128 KiB: per operand 2 K-tile buffers x 2 k-half regions
// (region = [256 rows][32 k] f16 = 16 KiB = 2 gload calls).
// Counted waits: vmcnt(6) at even phases (steady-state outstanding <= 10,
// wait completes the 2+2 loads of the region needed NEXT phase; two
// barriers sit between wait and cross-wave use).
// ALWAYS-STAGE: final iteration stages dead data (k-source clamped to 0)
// so every iteration is exactly steady state -> waits provably sufficient
// (the skip-staging variant made final-iter residency timing-dependent).
template<int OMODE, int BIAS, bool RELU, int NX, int NY, int NZ>
__global__ __launch_bounds__(512) void gemm256(
    const u16* __restrict__ A, long lda, long Asb,
    const u16* __restrict__ B, long ldb, long Bsb,
    void* __restrict__ Cv, long ldc, long Csb, u16* __restrict__ C1,
    const float* __restrict__ bias, const float* __restrict__ bias2,
    const float* __restrict__ bias3, int K)
{
    constexpr int NWG = NX * NY * NZ;
    static_assert(NWG % 8 == 0, "XCD swizzle needs nwg % 8 == 0");
    alignas(16) __shared__ u16 As[4 * 8192];
    alignas(16) __shared__ u16 Bs[4 * 8192];

    const int tid = threadIdx.x;
    const int lane = tid & 63, wave = tid >> 6;
    const int l16 = lane & 15, quad = lane >> 4;
    const int wm = wave >> 2;              // 0..1  (M)
    const int wn = wave & 3;               // 0..3  (N)

    const int lin = blockIdx.x;
    const int tl = (lin & 7) * (NWG / 8) + (lin >> 3);
    const int xe = tl % NX;
    const int ye = (tl / NX) % NY;
    const int zb = tl / (NX * NY);
    const long m0 = (long)ye * 256;
    const long n0 = (long)xe * 256;

    const u16* Aop = A + (long)zb * Asb;
    const u16* Bop = B + (long)zb * Bsb;

    const int srow = tid >> 2;
    const int sq = (tid & 3) ^ ((tid >> 3) & 3);
    const long gaofs0 = (m0 + srow) * lda + sq * 8;
    const long gaofs1 = gaofs0 + 128 * lda;
    const long gbofs0 = (n0 + srow) * ldb + sq * 8;
    const long gbofs1 = gbofs0 + 128 * ldb;
    const int wv512n = wave * 512;

    const int swzE = (quad ^ ((l16 >> 1) & 3)) * 8;
    const int aRow = (wm * 128 + l16) * 32 + swzE;
    const int bRow = (wn * 64 + l16) * 32 + swzE;

    v4f acc[8][4];
#pragma unroll
    for (int i = 0; i < 8; ++i)
#pragma unroll
        for (int j = 0; j < 4; ++j)
            acc[i][j] = (v4f){0.f, 0.f, 0.f, 0.f};
    v8h bf[4];

#define STAGE_A(RIDX, KP) do { \
        u16* lb_ = As + (RIDX) * 8192 + wv512n; \
        gload_lds16(Aop + gaofs0 + (KP), lb_); \
        gload_lds16(Aop + gaofs1 + (KP), lb_ + 4096); } while (0)
#define STAGE_B(RIDX, KP) do { \
        u16* lb_ = Bs + (RIDX) * 8192 + wv512n; \
        gload_lds16(Bop + gbofs0 + (KP), lb_); \
        gload_lds16(Bop + gbofs1 + (KP), lb_ + 4096); } while (0)

#define MF(CH, I, J) \
    acc[(CH) * 4 + (I)][J] = __builtin_amdgcn_mfma_f32_16x16x32_f16( \
        af##I, bf[J], acc[(CH) * 4 + (I)][J], 0, 0, 0)

#define PHASE(BUF, KH, CH, EVENW, ...) { \
        if (EVENW) asm volatile("s_waitcnt vmcnt(6)" ::: "memory"); \
        const u16* Ar_ = As + ((BUF) * 2 + (KH)) * 8192 + aRow + (CH) * 2048; \
        v8h af0 = *(const v8h*)(Ar_); \
        v8h af1 = *(const v8h*)(Ar_ + 512); \
        v8h af2 = *(const v8h*)(Ar_ + 1024); \
        v8h af3 = *(const v8h*)(Ar_ + 1536); \
        if ((CH) == 0) { \
            const u16* Br_ = Bs + ((BUF) * 2 + (KH)) * 8192 + bRow; \
            bf[0] = *(const v8h*)(Br_); \
            bf[1] = *(const v8h*)(Br_ + 512); \
            bf[2] = *(const v8h*)(Br_ + 1024); \
            bf[3] = *(const v8h*)(Br_ + 1536); \
        } \
        __VA_ARGS__; \
        __builtin_amdgcn_s_barrier(); \
        asm volatile("s_waitcnt lgkmcnt(0)" ::: "memory"); \
        __builtin_amdgcn_s_setprio(1); \
        MF(CH,0,0); MF(CH,0,1); MF(CH,0,2); MF(CH,0,3); \
        MF(CH,1,0); MF(CH,1,1); MF(CH,1,2); MF(CH,1,3); \
        MF(CH,2,0); MF(CH,2,1); MF(CH,2,2); MF(CH,2,3); \
        MF(CH,3,0); MF(CH,3,1); MF(CH,3,2); MF(CH,3,3); \
        __builtin_amdgcn_s_setprio(0); \
        __builtin_amdgcn_s_barrier(); \
    }

    // prologue: r0,r1,r2 (12 loads); r0 resident after vmcnt(8)
    STAGE_A(0, 0);  STAGE_B(0, 0);
    STAGE_A(1, 32); STAGE_B(1, 32);
    STAGE_A(2, 64); STAGE_B(2, 64);
    asm volatile("s_waitcnt vmcnt(8)" ::: "memory");
    __builtin_amdgcn_s_barrier();

    const int NT = K >> 7;   // K % 128 == 0
#pragma unroll 1
    for (int t = 0; t < NT; ++t) {
        const long kb = (long)t * 128;
        const long kp1 = kb + 96;
        long kp2  = kb + 128; if (kp2  >= K) kp2  = 0;
        long kp2b = kb + 160; if (kp2b >= K) kp2b = 0;
        long kp3  = kb + 192; if (kp3  >= K) kp3  = 0;

        PHASE(0, 0, 0, false, STAGE_A(3, kp1))   // P1
        PHASE(0, 0, 1, true,  STAGE_B(3, kp1))   // P2
        PHASE(0, 1, 0, false, STAGE_A(0, kp2))   // P3
        PHASE(0, 1, 1, true,  STAGE_B(0, kp2))   // P4
        PHASE(1, 0, 0, false, STAGE_A(1, kp2b))  // P5
        PHASE(1, 0, 1, true,  STAGE_B(1, kp2b))  // P6
        PHASE(1, 1, 0, false, STAGE_A(2, kp3))   // P7
        PHASE(1, 1, 1, true,  STAGE_B(2, kp3))   // P8
    }

#undef PHASE
#undef MF
#undef STAGE_A
#undef STAGE_B

    float bv[4];
#pragma unroll
    for (int j = 0; j < 4; ++j) {
        const long col = n0 + wn * 64 + j * 16 + l16;
        if (BIAS == 0) bv[j] = 0.f;
        else if (BIAS == 1) bv[j] = bias[col];
        else {
            const int sel = (int)(col >> 10);
            const float* bp = sel == 0 ? bias : (sel == 1 ? bias2 : bias3);
            bv[j] = bp[col & 1023];
        }
    }

    if (OMODE == 3 && n0 >= 2048) {
        const long bb = m0 >> 11, mb = m0 & 2047;
        u16* C = C1 + bb * Csb;
#pragma unroll
        for (int j = 0; j < 4; ++j) {
            const long col = n0 - 2048 + wn * 64 + j * 16 + l16;
            u16* pc = C + col * 2048 + mb + wm * 128 + quad * 4;
#pragma unroll
            for (int i = 0; i < 8; ++i) {
                u16 o[4];
#pragma unroll
                for (int r = 0; r < 4; ++r) {
                    float val = acc[i][j][r] + bv[j];
                    if (RELU) val = fmaxf(val, 0.f);
                    o[r] = f2h(val);
                }
                *(uint2*)(pc + i * 16) = *(const uint2*)o;
            }
        }
    } else {
        const long cb = (OMODE == 3 ? 0 : (long)zb * Csb)
                      + (m0 + wm * 128 + quad * 4) * ldc + (n0 + wn * 64 + l16);
        u16* p0 = (u16*)Cv + cb;
#pragma unroll
        for (int i = 0; i < 8; ++i)
#pragma unroll
            for (int r = 0; r < 4; ++r) {
                u16* prow = p0 + (long)(i * 16 + r) * ldc;
#pragma unroll
                for (int j = 0; j < 4; ++j) {
                    float val = acc[i][j][r] + bv[j];
                    if (RELU) val = fmaxf(val, 0.f);
                    prow[j * 16] = f2h(val);
                }
            }
    }
}

// ======== 256x128 8-phase f16 GEMM: C = A @ B^T (+bias)(+relu) ========
// Same 8-phase schedule with BN=128 for N=1024 outputs (full-device grids:
// FF2/Wo 256 blocks, PV 8x8x4, QKV 24x32=768 = 3 full rounds).
// 8 waves 2M x 4N, per-wave 128x32 output (acc[8][2]).
// Regions: A = [256][32] f16 (2 gload calls), B = [128][32] (1 call);
// LDS = 64 + 32 = 96 KiB. 12 loads per 8-phase iteration.
// Wait derivation (wait-one-phase-ahead, FIFO vmcnt):
//   steady state at even-phase top: outstanding = 8
//   vmcnt(5) completes exactly the 3 loads (2A+1B) of the region consumed
//   next phase; two barriers between wait and cross-wave use.
// Always-stage (clamped k) -> every iteration is steady state.
template<int OMODE, int BIAS, bool RELU, int NX, int NY, int NZ>
__global__ __launch_bounds__(512) void gemm256n(
    const u16* __restrict__ A, long lda, long Asb,
    const u16* __restrict__ B, long ldb, long Bsb,
    void* __restrict__ Cv, long ldc, long Csb, u16* __restrict__ C1,
    const float* __restrict__ bias, const float* __restrict__ bias2,
    const float* __restrict__ bias3, int K)
{
    constexpr int NWG = NX * NY * NZ;
    static_assert(NWG % 8 == 0, "XCD swizzle needs nwg % 8 == 0");
    alignas(16) __shared__ u16 As[4 * 8192];   // 64 KiB
    alignas(16) __shared__ u16 Bs[4 * 4096];   // 32 KiB

    const int tid = threadIdx.x;
    const int lane = tid & 63, wave = tid >> 6;
    const int l16 = lane & 15, quad = lane >> 4;
    const int wm = wave >> 2;              // 0..1 (M, 128 rows each)
    const int wn = wave & 3;               // 0..3 (N, 32 cols each)

    const int lin = blockIdx.x;
    const int tl = (lin & 7) * (NWG / 8) + (lin >> 3);
    const int xe = tl % NX;
    const int ye = (tl / NX) % NY;
    const int zb = tl / (NX * NY);
    const long m0 = (long)ye * 256;
    const long n0 = (long)xe * 128;

    const u16* Aop = A + (long)zb * Asb;
    const u16* Bop = B + (long)zb * Bsb;

    const int srow = tid >> 2;                       // 0..127
    const int sq = (tid & 3) ^ ((tid >> 3) & 3);
    const long gaofs0 = (m0 + srow) * lda + sq * 8;
    const long gaofs1 = gaofs0 + 128 * lda;
    const long gbofs0 = (n0 + srow) * ldb + sq * 8;  // B region = 128 rows
    const int wv512n = wave * 512;

    const int swzE = (quad ^ ((l16 >> 1) & 3)) * 8;
    const int aRow = (wm * 128 + l16) * 32 + swzE;
    const int bRow = (wn * 32 + l16) * 32 + swzE;

    v4f acc[8][2];
#pragma unroll
    for (int i = 0; i < 8; ++i)
#pragma unroll
        for (int j = 0; j < 2; ++j)
            acc[i][j] = (v4f){0.f, 0.f, 0.f, 0.f};
    v8h bf[2];

#define STAGE_A(RIDX, KP) do { \
        u16* lb_ = As + (RIDX) * 8192 + wv512n; \
        gload_lds16(Aop + gaofs0 + (KP), lb_); \
        gload_lds16(Aop + gaofs1 + (KP), lb_ + 4096); } while (0)
#define STAGE_B(RIDX, KP) do { \
        gload_lds16(Bop + gbofs0 + (KP), Bs + (RIDX) * 4096 + wv512n); } while (0)

#define MF(CH, I, J) \
    acc[(CH) * 4 + (I)][J] = __builtin_amdgcn_mfma_f32_16x16x32_f16( \
        af##I, bf[J], acc[(CH) * 4 + (I)][J], 0, 0, 0)

#define PHASE(BUF, KH, CH, EVENW, ...) { \
        if (EVENW) asm volatile("s_waitcnt vmcnt(5)" ::: "memory"); \
        const u16* Ar_ = As + ((BUF) * 2 + (KH)) * 8192 + aRow + (CH) * 2048; \
        v8h af0 = *(const v8h*)(Ar_); \
        v8h af1 = *(const v8h*)(Ar_ + 512); \
        v8h af2 = *(const v8h*)(Ar_ + 1024); \
        v8h af3 = *(const v8h*)(Ar_ + 1536); \
        if ((CH) == 0) { \
            const u16* Br_ = Bs + ((BUF) * 2 + (KH)) * 4096 + bRow; \
            bf[0] = *(const v8h*)(Br_); \
            bf[1] = *(const v8h*)(Br_ + 512); \
        } \
        __VA_ARGS__; \
        __builtin_amdgcn_s_barrier(); \
        asm volatile("s_waitcnt lgkmcnt(0)" ::: "memory"); \
        __builtin_amdgcn_s_setprio(1); \
        MF(CH,0,0); MF(CH,0,1); \
        MF(CH,1,0); MF(CH,1,1); \
        MF(CH,2,0); MF(CH,2,1); \
        MF(CH,3,0); MF(CH,3,1); \
        __builtin_amdgcn_s_setprio(0); \
        __builtin_amdgcn_s_barrier(); \
    }

    // prologue: r0,r1,r2 (9 loads); r0 resident after vmcnt(6)
    STAGE_A(0, 0);  STAGE_B(0, 0);
    STAGE_A(1, 32); STAGE_B(1, 32);
    STAGE_A(2, 64); STAGE_B(2, 64);
    asm volatile("s_waitcnt vmcnt(6)" ::: "memory");
    __builtin_amdgcn_s_barrier();

    const int NT = K >> 7;   // K % 128 == 0
#pragma unroll 1
    for (int t = 0; t < NT; ++t) {
        const long kb = (long)t * 128;
        const long kp1 = kb + 96;
        long kp2  = kb + 128; if (kp2  >= K) kp2  = 0;
        long kp2b = kb + 160; if (kp2b >= K) kp2b = 0;
        long kp3  = kb + 192; if (kp3  >= K) kp3  = 0;

        PHASE(0, 0, 0, false, STAGE_A(3, kp1))   // P1
        PHASE(0, 0, 1, true,  STAGE_B(3, kp1))   // P2
        PHASE(0, 1, 0, false, STAGE_A(0, kp2))   // P3
        PHASE(0, 1, 1, true,  STAGE_B(0, kp2))   // P4
        PHASE(1, 0, 0, false, STAGE_A(1, kp2b))  // P5
        PHASE(1, 0, 1, true,  STAGE_B(1, kp2b))  // P6
        PHASE(1, 1, 0, false, STAGE_A(2, kp3))   // P7
        PHASE(1, 1, 1, true,  STAGE_B(2, kp3))   // P8
    }

#undef PHASE
#undef MF
#undef STAGE_A
#undef STAGE_B

    float bv[2];
#pragma unroll
    for (int j = 0; j < 2; ++j) {
        const long col = n0 + wn * 32 + j * 16 + l16;
        if (BIAS == 0) bv[j] = 0.f;
        else if (BIAS == 1) bv[j] = bias[col];
        else {
            const int sel = (int)(col >> 10);
            const float* bp = sel == 0 ? bias : (sel == 1 ? bias2 : bias3);
            bv[j] = bp[col & 1023];
        }
    }

    if (OMODE == 3 && n0 >= 2048) {
        const long bb = m0 >> 11, mb = m0 & 2047;
        u16* C = C1 + bb * Csb;
#pragma unroll
        for (int j = 0; j < 2; ++j) {
            const long col = n0 - 2048 + wn * 32 + j * 16 + l16;
            u16* pc = C + col * 2048 + mb + wm * 128 + quad * 4;
#pragma unroll
            for (int i = 0; i < 8; ++i) {
                u16 o[4];
#pragma unroll
                for (int r = 0; r < 4; ++r) {
                    float val = acc[i][j][r] + bv[j];
                    if (RELU) val = fmaxf(val, 0.f);
                    o[r] = f2h(val);
                }
                *(uint2*)(pc + i * 16) = *(const uint2*)o;
            }
        }
    } else {
        const long cb = (OMODE == 3 ? 0 : (long)zb * Csb)
                      + (m0 + wm * 128 + quad * 4) * ldc + (n0 + wn * 32 + l16);
        u16* p0 = (u16*)Cv + cb;
#pragma unroll
        for (int i = 0; i < 8; ++i)
#pragma unroll
            for (int r = 0; r < 4; ++r) {
                u16* prow = p0 + (long)(i * 16 + r) * ldc;
#pragma unroll
                for (int j = 0; j < 2; ++j) {
                    float val = acc[i][j][r] + bv[j];
                    if (RELU) val = fmaxf(val, 0.f);
                    prow[j * 16] = f2h(val);
                }
            }
    }
}

// ---------------- softmax over f16 rows of 2048, in place ----------------
__global__ __launch_bounds__(256) void softmax_rows(u16* __restrict__ S) {
    const long row = blockIdx.x;
    u16* p = S + row * 2048;
    const int t = threadIdx.x;
    float v[8];
    float mx = -1e30f;
#pragma unroll
    for (int i = 0; i < 8; ++i) { v[i] = h2f(p[t + i * 256]); mx = fmaxf(mx, v[i]); }
    __shared__ float red[256];
    red[t] = mx; __syncthreads();
    for (int off = 128; off > 0; off >>= 1) {
        if (t < off) red[t] = fmaxf(red[t], red[t + off]);
        __syncthreads();
    }
    mx = red[0]; __syncthreads();
    float sum = 0.f;
#pragma unroll
    for (int i = 0; i < 8; ++i) { v[i] = __expf(v[i] - mx); sum += v[i]; }
    red[t] = sum; __syncthreads();
    for (int off = 128; off > 0; off >>= 1) {
        if (t < off) red[t] += red[t + off];
        __syncthreads();
    }
    const float inv = 1.f / red[0];
#pragma unroll
    for (int i = 0; i < 8; ++i) p[t + i * 256] = f2h(v[i] * inv);
}

// ---------------- ln1: xh_f16 = LN(src_f32 + attnO_f16) ----------------
__global__ __launch_bounds__(256) void ln_one(
    const float* __restrict__ a, const u16* __restrict__ bb,
    const float* __restrict__ g, const float* __restrict__ be,
    u16* __restrict__ out16)
{
    const long base = (long)blockIdx.x * 1024;
    const int t = threadIdx.x;
    float v[4]; float s = 0.f, ss = 0.f;
#pragma unroll
    for (int i = 0; i < 4; ++i) {
        const int c = t + i * 256;
        const float x = a[base + c] + h2f(bb[base + c]);
        v[i] = x; s += x; ss += x * x;
    }
    __shared__ float rs[256], rss[256];
    rs[t] = s; rss[t] = ss; __syncthreads();
    for (int off = 128; off > 0; off >>= 1) {
        if (t < off) { rs[t] += rs[t + off]; rss[t] += rss[t + off]; }
        __syncthreads();
    }
    const float mean = rs[0] * (1.f / 1024.f);
    const float var = rss[0] * (1.f / 1024.f) - mean * mean;
    const float rstd = rsqrtf(var + 1e-5f);
#pragma unroll
    for (int i = 0; i < 4; ++i) {
        const int c = t + i * 256;
        out16[base + c] = f2h((v[i] - mean) * rstd * g[c] + be[c]);
    }
}

// ---------------- ln2: out_f32 = LN(xh_f16 + ffO_f16) ----------------
__global__ __launch_bounds__(256) void ln_two(
    const u16* __restrict__ a, const u16* __restrict__ bb,
    const float* __restrict__ g, const float* __restrict__ be,
    float* __restrict__ out)
{
    const long base = (long)blockIdx.x * 1024;
    const int t = threadIdx.x;
    float v[4]; float s = 0.f, ss = 0.f;
#pragma unroll
    for (int i = 0; i < 4; ++i) {
        const int c = t + i * 256;
        const float x = h2f(a[base + c]) + h2f(bb[base + c]);
        v[i] = x; s += x; ss += x * x;
    }
    __shared__ float rs[256], rss[256];
    rs[t] = s; rss[t] = ss; __syncthreads();
    for (int off = 128; off > 0; off >>= 1) {
        if (t < off) { rs[t] += rs[t + off]; rss[t] += rss[t + off]; }
        __syncthreads();
    }
    const float mean = rs[0] * (1.f / 1024.f);
    const float var = rss[0] * (1.f / 1024.f) - mean * mean;
    const float rstd = rsqrtf(var + 1e-5f);
#pragma unroll
    for (int i = 0; i < 4; ++i) {
        const int c = t + i * 256;
        out[base + c] = (v[i] - mean) * rstd * g[c] + be[c];
    }
}

extern "C" void kernel_launch(void* const* d_in, const int* in_sizes, int n_in,
                              void* d_out, int out_size, void* d_ws, size_t ws_size,
                              hipStream_t stream) {
    (void)in_sizes; (void)n_in; (void)out_size; (void)ws_size;
    constexpr long S = 2048, E = 1024, F = 4096, M = 8192;

    const float* src = (const float*)d_in[0];
    const float* Wq  = (const float*)d_in[1];
    const float* bq  = (const float*)d_in[2];
    const float* Wk  = (const float*)d_in[3];
    const float* bk  = (const float*)d_in[4];
    const float* Wv  = (const float*)d_in[5];
    const float* bv  = (const float*)d_in[6];
    const float* Wo  = (const float*)d_in[7];
    const float* bo  = (const float*)d_in[8];
    const float* W1  = (const float*)d_in[9];
    const float* b1  = (const float*)d_in[10];
    const float* W2  = (const float*)d_in[11];
    const float* b2  = (const float*)d_in[12];
    const float* g1  = (const float*)d_in[13];
    const float* be1 = (const float*)d_in[14];
    const float* g2  = (const float*)d_in[15];
    const float* be2 = (const float*)d_in[16];

    char* ws = (char*)d_ws;
    size_t off = 0;
    auto take = [&](size_t bytes) {
        char* p = ws + off;
        off += (bytes + 255) & ~(size_t)255;
        return p;
    };
    const size_t MB16 = 16777216;  // f16 [8192][1024]
    u16*   srcH  = (u16*)take(MB16);
    u16*   WqkvT = (u16*)take(3 * E * E * 2);     // [3072][1024]: WqT | WkT | WvT
    u16*   WoT   = (u16*)take(E * E * 2);
    u16*   W1T   = (u16*)take(F * E * 2);         // [4096][1024]
    u16*   W2T   = (u16*)take(E * F * 2);         // [1024][4096]
    char*  B0    = take(2 * MB16);                // QK f16 [8192][2048]
    char*  B1    = take(MB16);                    // VT f16 [4][1024][2048]
    char*  B2    = take(4ull * S * S * 4);        // Sh f16 (32M) -> hf f16 [8192][4096] (64M)
    char*  B3    = take(MB16);                    // attn f16 -> xh f16
    char*  B4    = take(MB16);                    // attnO f16 -> ffO f16

    u16*   QK    = (u16*)B0;
    u16*   VT    = (u16*)B1;
    u16*   Sh    = (u16*)B2;
    u16*   hf    = (u16*)B2;
    u16*   attn  = (u16*)B3;
    u16*   xh    = (u16*)B3;
    u16*   attnO = (u16*)B4;
    u16*   ffO   = (u16*)B4;

    dim3 blk(256), blk5(512), tb(32, 8);

    // 1) convert src -> f16
    cvt_f16<<<dim3(M * E / 8 / 256), blk, 0, stream>>>(src, srcH, M * E / 8);

    // 2) all weight transposes in one launch
    transpose_all<<<dim3(12288), tb, 0, stream>>>(Wq, Wk, Wv, Wo, W1, W2,
                                                  WqkvT, WoT, W1T, W2T);

    // 3) merged Q|K|V projection (8-phase 256x128): 768 blocks = 3 full rounds
    gemm256n<3, 3, false, 24, 32, 1><<<dim3(24 * 32), blk5, 0, stream>>>(
        srcH, E, 0, WqkvT, E, 0, QK, 2 * E, E * S, VT, bq, bk, bv, E);

    // 4) scores[b] = Q[b] @ K[b]^T (8-phase 256x256, 256 blocks)
    gemm256<0, 0, false, 8, 8, 4><<<dim3(8 * 8 * 4), blk5, 0, stream>>>(
        QK, 2 * E, S * 2 * E, QK + E, 2 * E, S * 2 * E,
        Sh, S, S * S, nullptr, nullptr, nullptr, nullptr, E);

    // 5) softmax in place (f16)
    softmax_rows<<<dim3(M), blk, 0, stream>>>(Sh);

    // 6) attn[b] = P[b] @ V[b] (8-phase 256x128, 256 blocks)
    gemm256n<0, 0, false, 8, 8, 4><<<dim3(8 * 8 * 4), blk5, 0, stream>>>(
        Sh, S, S * S, VT, S, E * S,
        attn, E, S * E, nullptr, nullptr, nullptr, nullptr, S);

    // 7) attnO = attn @ Wo + bo (8-phase 256x128, 256 blocks)
    gemm256n<0, 1, false, 8, 32, 1><<<dim3(8 * 32), blk5, 0, stream>>>(
        attn, E, 0, WoT, E, 0, attnO, E, 0, nullptr, bo, nullptr, nullptr, E);

    // 8) xh = LN(src + attnO) (f16, over dead attn)
    ln_one<<<dim3(M), blk, 0, stream>>>(src, attnO, g1, be1, xh);

    // 9) hf = relu(xh @ W1 + b1) (8-phase 256x256, 512 blocks = 2 rounds)
    gemm256<0, 1, true, 16, 32, 1><<<dim3(16 * 32), blk5, 0, stream>>>(
        xh, E, 0, W1T, E, 0, hf, F, 0, nullptr, b1, nullptr, nullptr, E);

    // 10) ffO = hf @ W2 + b2 (8-phase 256x128, 256 blocks, K=4096)
    gemm256n<0, 1, false, 8, 32, 1><<<dim3(8 * 32), blk5, 0, stream>>>(
        hf, F, 0, W2T, F, 0, ffO, E, 0, nullptr, b2, nullptr, nullptr, F);

    // 11) out = LN(xh + ffO) -> f32
    ln_two<<<dim3(M), blk, 0, stream>>>(xh, ffO, g2, be2, (float*)d_out);
}

// Round 4
// 504.487 us; speedup vs baseline: 1.1071x; 1.0081x over previous
//
#include <hip/hip_runtime.h>
#include <stdint.h>

typedef unsigned short u16;
typedef _Float16 v8h __attribute__((ext_vector_type(8)));
typedef float v4f __attribute__((ext_vector_type(4)));

static __device__ __forceinline__ float h2f(u16 u) {
    union { u16 s; _Float16 h; } v; v.s = u; return (float)v.h;
}
static __device__ __forceinline__ u16 f2h(float f) {
    union { u16 s; _Float16 h; } v; v.h = (_Float16)f; return v.s;
}

// async global->LDS, 16B per lane. lds dest = wave-uniform base + lane*16.
static __device__ __forceinline__ void gload_lds16(const u16* g, const u16* l) {
    __builtin_amdgcn_global_load_lds(
        (const __attribute__((address_space(1))) uint32_t*)(uintptr_t)g,
        (__attribute__((address_space(3))) uint32_t*)(uintptr_t)l,
        16, 0, 0);
}

// ---------------- convert f32 -> f16, vectorized x8 ----------------
__global__ __launch_bounds__(256) void cvt_f16(const float* __restrict__ in,
                                               u16* __restrict__ out, int n8) {
    const int i = blockIdx.x * 256 + threadIdx.x;
    if (i >= n8) return;
    const float4 a = ((const float4*)in)[2 * i];
    const float4 b = ((const float4*)in)[2 * i + 1];
    u16 o[8] = {f2h(a.x), f2h(a.y), f2h(a.z), f2h(a.w),
                f2h(b.x), f2h(b.y), f2h(b.z), f2h(b.w)};
    *(uint4*)(out + (size_t)i * 8) = *(const uint4*)o;
}

// ---------------- all weight transposes f32 [R][C] -> f16 [C][R], one launch ----------------
__global__ __launch_bounds__(256) void transpose_all(
    const float* __restrict__ Wq, const float* __restrict__ Wk,
    const float* __restrict__ Wv, const float* __restrict__ Wo,
    const float* __restrict__ W1, const float* __restrict__ W2,
    u16* __restrict__ WqkvT, u16* __restrict__ WoT,
    u16* __restrict__ W1T, u16* __restrict__ W2T)
{
    int t = blockIdx.x;
    const float* in; u16* out; long ldi, ldo; int xt;
    if (t < 1024)      {            in = Wq; out = WqkvT;               ldi = 1024; ldo = 1024; xt = 32; }
    else if (t < 2048) { t -= 1024; in = Wk; out = WqkvT + 1024*1024;   ldi = 1024; ldo = 1024; xt = 32; }
    else if (t < 3072) { t -= 2048; in = Wv; out = WqkvT + 2*1024*1024; ldi = 1024; ldo = 1024; xt = 32; }
    else if (t < 4096) { t -= 3072; in = Wo; out = WoT;                 ldi = 1024; ldo = 1024; xt = 32; }
    else if (t < 8192) { t -= 4096; in = W1; out = W1T;                 ldi = 4096; ldo = 1024; xt = 128; }
    else               { t -= 8192; in = W2; out = W2T;                 ldi = 1024; ldo = 4096; xt = 32; }
    const int c0 = (t % xt) * 32, r0 = (t / xt) * 32;
    __shared__ float tile[32][33];
    for (int i = threadIdx.y; i < 32; i += 8)
        tile[i][threadIdx.x] = in[(long)(r0 + i) * ldi + c0 + threadIdx.x];
    __syncthreads();
    for (int i = threadIdx.y; i < 32; i += 8)
        out[(long)(c0 + i) * ldo + r0 + threadIdx.x] = f2h(tile[threadIdx.x][i]);
}

// ======== 256x256 8-window OVERLAPPED f16 GEMM (scores + FF1 only this round) ========
// Single-barrier windows, read-one-ahead: W(p) = { stage; setprio(1);
// MFMA(p) interleaved with ds_reads for W(p+1); setprio(0);
// [odd W: vmcnt(6)]; s_barrier }. Hardened: full drain after K-loop.
// vmcnt(6) at end of odd windows completes exactly the region consumed
// next window (2A+2B+2A newer loads); prologue vmcnt(8) covers r0.
// Re-staging region S in W(p) is safe: S's reads were issued in W(p-2)
// and drained (compiler lgkm waits before MFMA use) before the end-W(p-1)
// barrier. A-frags single-banked (WAR after consumption); B-frags
// double-banked. Accumulation order identical to the two-barrier kernel.
template<int OMODE, int BIAS, bool RELU, int NX, int NY, int NZ>
__global__ __launch_bounds__(512) void gemm256(
    const u16* __restrict__ A, long lda, long Asb,
    const u16* __restrict__ B, long ldb, long Bsb,
    void* __restrict__ Cv, long ldc, long Csb, u16* __restrict__ C1,
    const float* __restrict__ bias, const float* __restrict__ bias2,
    const float* __restrict__ bias3, int K)
{
    constexpr int NWG = NX * NY * NZ;
    static_assert(NWG % 8 == 0, "XCD swizzle needs nwg % 8 == 0");
    alignas(16) __shared__ u16 As[4 * 8192];
    alignas(16) __shared__ u16 Bs[4 * 8192];

    const int tid = threadIdx.x;
    const int lane = tid & 63, wave = tid >> 6;
    const int l16 = lane & 15, quad = lane >> 4;
    const int wm = wave >> 2;              // 0..1  (M)
    const int wn = wave & 3;               // 0..3  (N)

    const int lin = blockIdx.x;
    const int tl = (lin & 7) * (NWG / 8) + (lin >> 3);
    const int xe = tl % NX;
    const int ye = (tl / NX) % NY;
    const int zb = tl / (NX * NY);
    const long m0 = (long)ye * 256;
    const long n0 = (long)xe * 256;

    const u16* Aop = A + (long)zb * Asb;
    const u16* Bop = B + (long)zb * Bsb;

    const int srow = tid >> 2;
    const int sq = (tid & 3) ^ ((tid >> 3) & 3);
    const long gaofs0 = (m0 + srow) * lda + sq * 8;
    const long gaofs1 = gaofs0 + 128 * lda;
    const long gbofs0 = (n0 + srow) * ldb + sq * 8;
    const long gbofs1 = gbofs0 + 128 * ldb;
    const int wv512n = wave * 512;

    const int swzE = (quad ^ ((l16 >> 1) & 3)) * 8;
    const int aRow = (wm * 128 + l16) * 32 + swzE;
    const int bRow = (wn * 64 + l16) * 32 + swzE;

    v4f acc[8][4];
#pragma unroll
    for (int i = 0; i < 8; ++i)
#pragma unroll
        for (int j = 0; j < 4; ++j)
            acc[i][j] = (v4f){0.f, 0.f, 0.f, 0.f};
    v8h af[4];
    v8h bfr[2][4];

#define STAGE_A(RIDX, KP) do { \
        u16* lb_ = As + (RIDX) * 8192 + wv512n; \
        gload_lds16(Aop + gaofs0 + (KP), lb_); \
        gload_lds16(Aop + gaofs1 + (KP), lb_ + 4096); } while (0)
#define STAGE_B(RIDX, KP) do { \
        u16* lb_ = Bs + (RIDX) * 8192 + wv512n; \
        gload_lds16(Bop + gbofs0 + (KP), lb_); \
        gload_lds16(Bop + gbofs1 + (KP), lb_ + 4096); } while (0)

#define MF4(CH, I, BC) \
    acc[(CH)*4+(I)][0] = __builtin_amdgcn_mfma_f32_16x16x32_f16(af[I], bfr[BC][0], acc[(CH)*4+(I)][0], 0, 0, 0); \
    acc[(CH)*4+(I)][1] = __builtin_amdgcn_mfma_f32_16x16x32_f16(af[I], bfr[BC][1], acc[(CH)*4+(I)][1], 0, 0, 0); \
    acc[(CH)*4+(I)][2] = __builtin_amdgcn_mfma_f32_16x16x32_f16(af[I], bfr[BC][2], acc[(CH)*4+(I)][2], 0, 0, 0); \
    acc[(CH)*4+(I)][3] = __builtin_amdgcn_mfma_f32_16x16x32_f16(af[I], bfr[BC][3], acc[(CH)*4+(I)][3], 0, 0, 0);

#define PHASE(CH, BC, NRD, NCH, BLN, BN, ODD, STG) { \
        STG; \
        __builtin_amdgcn_s_setprio(1); \
        MF4(CH, 0, BC) \
        MF4(CH, 1, BC) \
        { const u16* Ar_ = As + (NRD) * 8192 + aRow + (NCH) * 2048; \
          af[0] = *(const v8h*)(Ar_); \
          af[1] = *(const v8h*)(Ar_ + 512); \
          if (BLN) { const u16* Br_ = Bs + (NRD) * 8192 + bRow; \
            bfr[BN][0] = *(const v8h*)(Br_); \
            bfr[BN][1] = *(const v8h*)(Br_ + 512); \
            bfr[BN][2] = *(const v8h*)(Br_ + 1024); \
            bfr[BN][3] = *(const v8h*)(Br_ + 1536); } } \
        MF4(CH, 2, BC) \
        { const u16* Ar_ = As + (NRD) * 8192 + aRow + (NCH) * 2048; \
          af[2] = *(const v8h*)(Ar_ + 1024); } \
        MF4(CH, 3, BC) \
        { const u16* Ar_ = As + (NRD) * 8192 + aRow + (NCH) * 2048; \
          af[3] = *(const v8h*)(Ar_ + 1536); } \
        __builtin_amdgcn_s_setprio(0); \
        if (ODD) asm volatile("s_waitcnt vmcnt(6)" ::: "memory"); \
        __builtin_amdgcn_s_barrier(); \
    }

    // prologue: regions r0,r1,r2 (12 loads); r0 resident after vmcnt(8)
    STAGE_A(0, 0);  STAGE_B(0, 0);
    STAGE_A(1, 32); STAGE_B(1, 32);
    STAGE_A(2, 64); STAGE_B(2, 64);
    asm volatile("s_waitcnt vmcnt(8)" ::: "memory");
    __builtin_amdgcn_s_barrier();

    // pre-loop fragment reads: r0 / CH0 (A) + r0 (B bank0)
#pragma unroll
    for (int i = 0; i < 4; ++i) af[i] = *(const v8h*)&As[aRow + i * 512];
#pragma unroll
    for (int j = 0; j < 4; ++j) bfr[0][j] = *(const v8h*)&Bs[bRow + j * 512];

    const int NT = K >> 7;   // K % 128 == 0
#pragma unroll 1
    for (int t = 0; t < NT; ++t) {
        const long kb = (long)t * 128;
        const long kp1 = kb + 96;
        long kp2  = kb + 128; if (kp2  >= K) kp2  = 0;
        long kp2b = kb + 160; if (kp2b >= K) kp2b = 0;
        long kp3  = kb + 192; if (kp3  >= K) kp3  = 0;

        //    CH BC  NRD NCH BLN BN ODD  stage
        PHASE(0, 0,  0,  1,  0, 0, 1, STAGE_A(3, kp1))   // W1: r0/CH0; rd r0/CH1
        PHASE(1, 0,  1,  0,  1, 1, 0, STAGE_B(3, kp1))   // W2: r0/CH1; rd r1/CH0 + B1
        PHASE(0, 1,  1,  1,  0, 0, 1, STAGE_A(0, kp2))   // W3: r1/CH0; rd r1/CH1
        PHASE(1, 1,  2,  0,  1, 0, 0, STAGE_B(0, kp2))   // W4: r1/CH1; rd r2/CH0 + B0
        PHASE(0, 0,  2,  1,  0, 0, 1, STAGE_A(1, kp2b))  // W5: r2/CH0; rd r2/CH1
        PHASE(1, 0,  3,  0,  1, 1, 0, STAGE_B(1, kp2b))  // W6: r2/CH1; rd r3/CH0 + B1
        PHASE(0, 1,  3,  1,  0, 0, 1, STAGE_A(2, kp3))   // W7: r3/CH0; rd r3/CH1
        PHASE(1, 1,  0,  0,  1, 0, 0, STAGE_B(2, kp3))   // W8: r3/CH1; rd r0/CH0 + B0
    }

    // hardened: drain all outstanding DMA/LDS ops before epilogue/endpgm
    asm volatile("s_waitcnt vmcnt(0) lgkmcnt(0)" ::: "memory");
    __builtin_amdgcn_s_barrier();

#undef PHASE
#undef MF4
#undef STAGE_A
#undef STAGE_B

    float bv[4];
#pragma unroll
    for (int j = 0; j < 4; ++j) {
        const long col = n0 + wn * 64 + j * 16 + l16;
        if (BIAS == 0) bv[j] = 0.f;
        else if (BIAS == 1) bv[j] = bias[col];
        else {
            const int sel = (int)(col >> 10);
            const float* bp = sel == 0 ? bias : (sel == 1 ? bias2 : bias3);
            bv[j] = bp[col & 1023];
        }
    }

    if (OMODE == 3 && n0 >= 2048) {
        const long bb = m0 >> 11, mb = m0 & 2047;
        u16* C = C1 + bb * Csb;
#pragma unroll
        for (int j = 0; j < 4; ++j) {
            const long col = n0 - 2048 + wn * 64 + j * 16 + l16;
            u16* pc = C + col * 2048 + mb + wm * 128 + quad * 4;
#pragma unroll
            for (int i = 0; i < 8; ++i) {
                u16 o[4];
#pragma unroll
                for (int r = 0; r < 4; ++r) {
                    float val = acc[i][j][r] + bv[j];
                    if (RELU) val = fmaxf(val, 0.f);
                    o[r] = f2h(val);
                }
                *(uint2*)(pc + i * 16) = *(const uint2*)o;
            }
        }
    } else {
        const long cb = (OMODE == 3 ? 0 : (long)zb * Csb)
                      + (m0 + wm * 128 + quad * 4) * ldc + (n0 + wn * 64 + l16);
        u16* p0 = (u16*)Cv + cb;
#pragma unroll
        for (int i = 0; i < 8; ++i)
#pragma unroll
            for (int r = 0; r < 4; ++r) {
                u16* prow = p0 + (long)(i * 16 + r) * ldc;
#pragma unroll
                for (int j = 0; j < 4; ++j) {
                    float val = acc[i][j][r] + bv[j];
                    if (RELU) val = fmaxf(val, 0.f);
                    prow[j * 16] = f2h(val);
                }
            }
    }
}

// ======== 256x128 8-phase f16 GEMM (two-barrier, PROVEN round-2 code) ========
// Used for QKV / PV / Wo / FF2 this round (bisection: only the 256x256
// kernel carries the new overlapped schedule).
template<int OMODE, int BIAS, bool RELU, int NX, int NY, int NZ>
__global__ __launch_bounds__(512) void gemm256n(
    const u16* __restrict__ A, long lda, long Asb,
    const u16* __restrict__ B, long ldb, long Bsb,
    void* __restrict__ Cv, long ldc, long Csb, u16* __restrict__ C1,
    const float* __restrict__ bias, const float* __restrict__ bias2,
    const float* __restrict__ bias3, int K)
{
    constexpr int NWG = NX * NY * NZ;
    static_assert(NWG % 8 == 0, "XCD swizzle needs nwg % 8 == 0");
    alignas(16) __shared__ u16 As[4 * 8192];   // 64 KiB
    alignas(16) __shared__ u16 Bs[4 * 4096];   // 32 KiB

    const int tid = threadIdx.x;
    const int lane = tid & 63, wave = tid >> 6;
    const int l16 = lane & 15, quad = lane >> 4;
    const int wm = wave >> 2;              // 0..1 (M, 128 rows each)
    const int wn = wave & 3;               // 0..3 (N, 32 cols each)

    const int lin = blockIdx.x;
    const int tl = (lin & 7) * (NWG / 8) + (lin >> 3);
    const int xe = tl % NX;
    const int ye = (tl / NX) % NY;
    const int zb = tl / (NX * NY);
    const long m0 = (long)ye * 256;
    const long n0 = (long)xe * 128;

    const u16* Aop = A + (long)zb * Asb;
    const u16* Bop = B + (long)zb * Bsb;

    const int srow = tid >> 2;                       // 0..127
    const int sq = (tid & 3) ^ ((tid >> 3) & 3);
    const long gaofs0 = (m0 + srow) * lda + sq * 8;
    const long gaofs1 = gaofs0 + 128 * lda;
    const long gbofs0 = (n0 + srow) * ldb + sq * 8;  // B region = 128 rows
    const int wv512n = wave * 512;

    const int swzE = (quad ^ ((l16 >> 1) & 3)) * 8;
    const int aRow = (wm * 128 + l16) * 32 + swzE;
    const int bRow = (wn * 32 + l16) * 32 + swzE;

    v4f acc[8][2];
#pragma unroll
    for (int i = 0; i < 8; ++i)
#pragma unroll
        for (int j = 0; j < 2; ++j)
            acc[i][j] = (v4f){0.f, 0.f, 0.f, 0.f};
    v8h bf[2];

#define STAGE_A(RIDX, KP) do { \
        u16* lb_ = As + (RIDX) * 8192 + wv512n; \
        gload_lds16(Aop + gaofs0 + (KP), lb_); \
        gload_lds16(Aop + gaofs1 + (KP), lb_ + 4096); } while (0)
#define STAGE_B(RIDX, KP) do { \
        gload_lds16(Bop + gbofs0 + (KP), Bs + (RIDX) * 4096 + wv512n); } while (0)

#define MF2(CH, I) \
    acc[(CH) * 4 + (I)][0] = __builtin_amdgcn_mfma_f32_16x16x32_f16(af[I], bf[0], acc[(CH) * 4 + (I)][0], 0, 0, 0); \
    acc[(CH) * 4 + (I)][1] = __builtin_amdgcn_mfma_f32_16x16x32_f16(af[I], bf[1], acc[(CH) * 4 + (I)][1], 0, 0, 0);

#define PHASE(BUF, KH, CH, EVENW, ...) { \
        if (EVENW) asm volatile("s_waitcnt vmcnt(5)" ::: "memory"); \
        const u16* Ar_ = As + ((BUF) * 2 + (KH)) * 8192 + aRow + (CH) * 2048; \
        v8h af[4]; \
        af[0] = *(const v8h*)(Ar_); \
        af[1] = *(const v8h*)(Ar_ + 512); \
        af[2] = *(const v8h*)(Ar_ + 1024); \
        af[3] = *(const v8h*)(Ar_ + 1536); \
        if ((CH) == 0) { \
            const u16* Br_ = Bs + ((BUF) * 2 + (KH)) * 4096 + bRow; \
            bf[0] = *(const v8h*)(Br_); \
            bf[1] = *(const v8h*)(Br_ + 512); \
        } \
        __VA_ARGS__; \
        __builtin_amdgcn_s_barrier(); \
        asm volatile("s_waitcnt lgkmcnt(0)" ::: "memory"); \
        __builtin_amdgcn_s_setprio(1); \
        MF2(CH, 0) \
        MF2(CH, 1) \
        MF2(CH, 2) \
        MF2(CH, 3) \
        __builtin_amdgcn_s_setprio(0); \
        __builtin_amdgcn_s_barrier(); \
    }

    // prologue: r0,r1,r2 (9 loads); r0 resident after vmcnt(6)
    STAGE_A(0, 0);  STAGE_B(0, 0);
    STAGE_A(1, 32); STAGE_B(1, 32);
    STAGE_A(2, 64); STAGE_B(2, 64);
    asm volatile("s_waitcnt vmcnt(6)" ::: "memory");
    __builtin_amdgcn_s_barrier();

    const int NT = K >> 7;   // K % 128 == 0
#pragma unroll 1
    for (int t = 0; t < NT; ++t) {
        const long kb = (long)t * 128;
        const long kp1 = kb + 96;
        long kp2  = kb + 128; if (kp2  >= K) kp2  = 0;
        long kp2b = kb + 160; if (kp2b >= K) kp2b = 0;
        long kp3  = kb + 192; if (kp3  >= K) kp3  = 0;

        PHASE(0, 0, 0, false, STAGE_A(3, kp1))   // P1
        PHASE(0, 0, 1, true,  STAGE_B(3, kp1))   // P2
        PHASE(0, 1, 0, false, STAGE_A(0, kp2))   // P3
        PHASE(0, 1, 1, true,  STAGE_B(0, kp2))   // P4
        PHASE(1, 0, 0, false, STAGE_A(1, kp2b))  // P5
        PHASE(1, 0, 1, true,  STAGE_B(1, kp2b))  // P6
        PHASE(1, 1, 0, false, STAGE_A(2, kp3))   // P7
        PHASE(1, 1, 1, true,  STAGE_B(2, kp3))   // P8
    }

#undef PHASE
#undef MF2
#undef STAGE_A
#undef STAGE_B

    float bv[2];
#pragma unroll
    for (int j = 0; j < 2; ++j) {
        const long col = n0 + wn * 32 + j * 16 + l16;
        if (BIAS == 0) bv[j] = 0.f;
        else if (BIAS == 1) bv[j] = bias[col];
        else {
            const int sel = (int)(col >> 10);
            const float* bp = sel == 0 ? bias : (sel == 1 ? bias2 : bias3);
            bv[j] = bp[col & 1023];
        }
    }

    if (OMODE == 3 && n0 >= 2048) {
        const long bb = m0 >> 11, mb = m0 & 2047;
        u16* C = C1 + bb * Csb;
#pragma unroll
        for (int j = 0; j < 2; ++j) {
            const long col = n0 - 2048 + wn * 32 + j * 16 + l16;
            u16* pc = C + col * 2048 + mb + wm * 128 + quad * 4;
#pragma unroll
            for (int i = 0; i < 8; ++i) {
                u16 o[4];
#pragma unroll
                for (int r = 0; r < 4; ++r) {
                    float val = acc[i][j][r] + bv[j];
                    if (RELU) val = fmaxf(val, 0.f);
                    o[r] = f2h(val);
                }
                *(uint2*)(pc + i * 16) = *(const uint2*)o;
            }
        }
    } else {
        const long cb = (OMODE == 3 ? 0 : (long)zb * Csb)
                      + (m0 + wm * 128 + quad * 4) * ldc + (n0 + wn * 32 + l16);
        u16* p0 = (u16*)Cv + cb;
#pragma unroll
        for (int i = 0; i < 8; ++i)
#pragma unroll
            for (int r = 0; r < 4; ++r) {
                u16* prow = p0 + (long)(i * 16 + r) * ldc;
#pragma unroll
                for (int j = 0; j < 2; ++j) {
                    float val = acc[i][j][r] + bv[j];
                    if (RELU) val = fmaxf(val, 0.f);
                    prow[j * 16] = f2h(val);
                }
            }
    }
}

// ---------------- softmax over f16 rows of 2048, in place ----------------
__global__ __launch_bounds__(256) void softmax_rows(u16* __restrict__ S) {
    const long row = blockIdx.x;
    u16* p = S + row * 2048;
    const int t = threadIdx.x;
    float v[8];
    float mx = -1e30f;
#pragma unroll
    for (int i = 0; i < 8; ++i) { v[i] = h2f(p[t + i * 256]); mx = fmaxf(mx, v[i]); }
    __shared__ float red[256];
    red[t] = mx; __syncthreads();
    for (int off = 128; off > 0; off >>= 1) {
        if (t < off) red[t] = fmaxf(red[t], red[t + off]);
        __syncthreads();
    }
    mx = red[0]; __syncthreads();
    float sum = 0.f;
#pragma unroll
    for (int i = 0; i < 8; ++i) { v[i] = __expf(v[i] - mx); sum += v[i]; }
    red[t] = sum; __syncthreads();
    for (int off = 128; off > 0; off >>= 1) {
        if (t < off) red[t] += red[t + off];
        __syncthreads();
    }
    const float inv = 1.f / red[0];
#pragma unroll
    for (int i = 0; i < 8; ++i) p[t + i * 256] = f2h(v[i] * inv);
}

// ---------------- ln1: xh_f16 = LN(src_f32 + attnO_f16) ----------------
__global__ __launch_bounds__(256) void ln_one(
    const float* __restrict__ a, const u16* __restrict__ bb,
    const float* __restrict__ g, const float* __restrict__ be,
    u16* __restrict__ out16)
{
    const long base = (long)blockIdx.x * 1024;
    const int t = threadIdx.x;
    float v[4]; float s = 0.f, ss = 0.f;
#pragma unroll
    for (int i = 0; i < 4; ++i) {
        const int c = t + i * 256;
        const float x = a[base + c] + h2f(bb[base + c]);
        v[i] = x; s += x; ss += x * x;
    }
    __shared__ float rs[256], rss[256];
    rs[t] = s; rss[t] = ss; __syncthreads();
    for (int off = 128; off > 0; off >>= 1) {
        if (t < off) { rs[t] += rs[t + off]; rss[t] += rss[t + off]; }
        __syncthreads();
    }
    const float mean = rs[0] * (1.f / 1024.f);
    const float var = rss[0] * (1.f / 1024.f) - mean * mean;
    const float rstd = rsqrtf(var + 1e-5f);
#pragma unroll
    for (int i = 0; i < 4; ++i) {
        const int c = t + i * 256;
        out16[base + c] = f2h((v[i] - mean) * rstd * g[c] + be[c]);
    }
}

// ---------------- ln2: out_f32 = LN(xh_f16 + ffO_f16) ----------------
__global__ __launch_bounds__(256) void ln_two(
    const u16* __restrict__ a, const u16* __restrict__ bb,
    const float* __restrict__ g, const float* __restrict__ be,
    float* __restrict__ out)
{
    const long base = (long)blockIdx.x * 1024;
    const int t = threadIdx.x;
    float v[4]; float s = 0.f, ss = 0.f;
#pragma unroll
    for (int i = 0; i < 4; ++i) {
        const int c = t + i * 256;
        const float x = h2f(a[base + c]) + h2f(bb[base + c]);
        v[i] = x; s += x; ss += x * x;
    }
    __shared__ float rs[256], rss[256];
    rs[t] = s; rss[t] = ss; __syncthreads();
    for (int off = 128; off > 0; off >>= 1) {
        if (t < off) { rs[t] += rs[t + off]; rss[t] += rss[t + off]; }
        __syncthreads();
    }
    const float mean = rs[0] * (1.f / 1024.f);
    const float var = rss[0] * (1.f / 1024.f) - mean * mean;
    const float rstd = rsqrtf(var + 1e-5f);
#pragma unroll
    for (int i = 0; i < 4; ++i) {
        const int c = t + i * 256;
        out[base + c] = (v[i] - mean) * rstd * g[c] + be[c];
    }
}

extern "C" void kernel_launch(void* const* d_in, const int* in_sizes, int n_in,
                              void* d_out, int out_size, void* d_ws, size_t ws_size,
                              hipStream_t stream) {
    (void)in_sizes; (void)n_in; (void)out_size; (void)ws_size;
    constexpr long S = 2048, E = 1024, F = 4096, M = 8192;

    const float* src = (const float*)d_in[0];
    const float* Wq  = (const float*)d_in[1];
    const float* bq  = (const float*)d_in[2];
    const float* Wk  = (const float*)d_in[3];
    const float* bk  = (const float*)d_in[4];
    const float* Wv  = (const float*)d_in[5];
    const float* bv  = (const float*)d_in[6];
    const float* Wo  = (const float*)d_in[7];
    const float* bo  = (const float*)d_in[8];
    const float* W1  = (const float*)d_in[9];
    const float* b1  = (const float*)d_in[10];
    const float* W2  = (const float*)d_in[11];
    const float* b2  = (const float*)d_in[12];
    const float* g1  = (const float*)d_in[13];
    const float* be1 = (const float*)d_in[14];
    const float* g2  = (const float*)d_in[15];
    const float* be2 = (const float*)d_in[16];

    char* ws = (char*)d_ws;
    size_t off = 0;
    auto take = [&](size_t bytes) {
        char* p = ws + off;
        off += (bytes + 255) & ~(size_t)255;
        return p;
    };
    const size_t MB16 = 16777216;  // f16 [8192][1024]
    u16*   srcH  = (u16*)take(MB16);
    u16*   WqkvT = (u16*)take(3 * E * E * 2);     // [3072][1024]: WqT | WkT | WvT
    u16*   WoT   = (u16*)take(E * E * 2);
    u16*   W1T   = (u16*)take(F * E * 2);         // [4096][1024]
    u16*   W2T   = (u16*)take(E * F * 2);         // [1024][4096]
    char*  B0    = take(2 * MB16);                // QK f16 [8192][2048]
    char*  B1    = take(MB16);                    // VT f16 [4][1024][2048]
    char*  B2    = take(4ull * S * S * 4);        // Sh f16 (32M) -> hf f16 [8192][4096] (64M)
    char*  B3    = take(MB16);                    // attn f16 -> xh f16
    char*  B4    = take(MB16);                    // attnO f16 -> ffO f16

    u16*   QK    = (u16*)B0;
    u16*   VT    = (u16*)B1;
    u16*   Sh    = (u16*)B2;
    u16*   hf    = (u16*)B2;
    u16*   attn  = (u16*)B3;
    u16*   xh    = (u16*)B3;
    u16*   attnO = (u16*)B4;
    u16*   ffO   = (u16*)B4;

    dim3 blk(256), blk5(512), tb(32, 8);

    // 1) convert src -> f16
    cvt_f16<<<dim3(M * E / 8 / 256), blk, 0, stream>>>(src, srcH, M * E / 8);

    // 2) all weight transposes in one launch
    transpose_all<<<dim3(12288), tb, 0, stream>>>(Wq, Wk, Wv, Wo, W1, W2,
                                                  WqkvT, WoT, W1T, W2T);

    // 3) merged Q|K|V projection (256x128 two-barrier): 768 blocks
    gemm256n<3, 3, false, 24, 32, 1><<<dim3(24 * 32), blk5, 0, stream>>>(
        srcH, E, 0, WqkvT, E, 0, QK, 2 * E, E * S, VT, bq, bk, bv, E);

    // 4) scores[b] = Q[b] @ K[b]^T (256x256 OVERLAPPED, 256 blocks)
    gemm256<0, 0, false, 8, 8, 4><<<dim3(8 * 8 * 4), blk5, 0, stream>>>(
        QK, 2 * E, S * 2 * E, QK + E, 2 * E, S * 2 * E,
        Sh, S, S * S, nullptr, nullptr, nullptr, nullptr, E);

    // 5) softmax in place (f16)
    softmax_rows<<<dim3(M), blk, 0, stream>>>(Sh);

    // 6) attn[b] = P[b] @ V[b] (256x128 two-barrier, 256 blocks)
    gemm256n<0, 0, false, 8, 8, 4><<<dim3(8 * 8 * 4), blk5, 0, stream>>>(
        Sh, S, S * S, VT, S, E * S,
        attn, E, S * E, nullptr, nullptr, nullptr, nullptr, S);

    // 7) attnO = attn @ Wo + bo (256x128 two-barrier, 256 blocks)
    gemm256n<0, 1, false, 8, 32, 1><<<dim3(8 * 32), blk5, 0, stream>>>(
        attn, E, 0, WoT, E, 0, attnO, E, 0, nullptr, bo, nullptr, nullptr, E);

    // 8) xh = LN(src + attnO) (f16, over dead attn)
    ln_one<<<dim3(M), blk, 0, stream>>>(src, attnO, g1, be1, xh);

    // 9) hf = relu(xh @ W1 + b1) (256x256 OVERLAPPED, 512 blocks)
    gemm256<0, 1, true, 16, 32, 1><<<dim3(16 * 32), blk5, 0, stream>>>(
        xh, E, 0, W1T, E, 0, hf, F, 0, nullptr, b1, nullptr, nullptr, E);

    // 10) ffO = hf @ W2 + b2 (256x128 two-barrier, 256 blocks, K=4096)
    gemm256n<0, 1, false, 8, 32, 1><<<dim3(8 * 32), blk5, 0, stream>>>(
        hf, F, 0, W2T, F, 0, ffO, E, 0, nullptr, b2, nullptr, nullptr, F);

    // 11) out = LN(xh + ffO) -> f32
    ln_two<<<dim3(M), blk, 0, stream>>>(xh, ffO, g2, be2, (float*)d_out);
}

// Round 5
// 499.154 us; speedup vs baseline: 1.1189x; 1.0107x over previous
//
#include <hip/hip_runtime.h>
#include <stdint.h>

typedef unsigned short u16;
typedef _Float16 v8h __attribute__((ext_vector_type(8)));
typedef float v4f __attribute__((ext_vector_type(4)));

static __device__ __forceinline__ float h2f(u16 u) {
    union { u16 s; _Float16 h; } v; v.s = u; return (float)v.h;
}
static __device__ __forceinline__ u16 f2h(float f) {
    union { u16 s; _Float16 h; } v; v.h = (_Float16)f; return v.s;
}

// async global->LDS, 16B per lane. lds dest = wave-uniform base + lane*16.
static __device__ __forceinline__ void gload_lds16(const u16* g, const u16* l) {
    __builtin_amdgcn_global_load_lds(
        (const __attribute__((address_space(1))) uint32_t*)(uintptr_t)g,
        (__attribute__((address_space(3))) uint32_t*)(uintptr_t)l,
        16, 0, 0);
}

// ---------------- convert f32 -> f16, vectorized x8 ----------------
__global__ __launch_bounds__(256) void cvt_f16(const float* __restrict__ in,
                                               u16* __restrict__ out, int n8) {
    const int i = blockIdx.x * 256 + threadIdx.x;
    if (i >= n8) return;
    const float4 a = ((const float4*)in)[2 * i];
    const float4 b = ((const float4*)in)[2 * i + 1];
    u16 o[8] = {f2h(a.x), f2h(a.y), f2h(a.z), f2h(a.w),
                f2h(b.x), f2h(b.y), f2h(b.z), f2h(b.w)};
    *(uint4*)(out + (size_t)i * 8) = *(const uint4*)o;
}

// ---------------- all weight transposes f32 [R][C] -> f16 [C][R], one launch ----------------
__global__ __launch_bounds__(256) void transpose_all(
    const float* __restrict__ Wq, const float* __restrict__ Wk,
    const float* __restrict__ Wv, const float* __restrict__ Wo,
    const float* __restrict__ W1, const float* __restrict__ W2,
    u16* __restrict__ WqkvT, u16* __restrict__ WoT,
    u16* __restrict__ W1T, u16* __restrict__ W2T)
{
    int t = blockIdx.x;
    const float* in; u16* out; long ldi, ldo; int xt;
    if (t < 1024)      {            in = Wq; out = WqkvT;               ldi = 1024; ldo = 1024; xt = 32; }
    else if (t < 2048) { t -= 1024; in = Wk; out = WqkvT + 1024*1024;   ldi = 1024; ldo = 1024; xt = 32; }
    else if (t < 3072) { t -= 2048; in = Wv; out = WqkvT + 2*1024*1024; ldi = 1024; ldo = 1024; xt = 32; }
    else if (t < 4096) { t -= 3072; in = Wo; out = WoT;                 ldi = 1024; ldo = 1024; xt = 32; }
    else if (t < 8192) { t -= 4096; in = W1; out = W1T;                 ldi = 4096; ldo = 1024; xt = 128; }
    else               { t -= 8192; in = W2; out = W2T;                 ldi = 1024; ldo = 4096; xt = 32; }
    const int c0 = (t % xt) * 32, r0 = (t / xt) * 32;
    __shared__ float tile[32][33];
    for (int i = threadIdx.y; i < 32; i += 8)
        tile[i][threadIdx.x] = in[(long)(r0 + i) * ldi + c0 + threadIdx.x];
    __syncthreads();
    for (int i = threadIdx.y; i < 32; i += 8)
        out[(long)(c0 + i) * ldo + r0 + threadIdx.x] = f2h(tile[threadIdx.x][i]);
}

// ======== 256x256 8-window OVERLAPPED f16 GEMM (scores + FF1) — round-4 passing version, unchanged ========
template<int OMODE, int BIAS, bool RELU, int NX, int NY, int NZ>
__global__ __launch_bounds__(512) void gemm256(
    const u16* __restrict__ A, long lda, long Asb,
    const u16* __restrict__ B, long ldb, long Bsb,
    void* __restrict__ Cv, long ldc, long Csb, u16* __restrict__ C1,
    const float* __restrict__ bias, const float* __restrict__ bias2,
    const float* __restrict__ bias3, int K)
{
    constexpr int NWG = NX * NY * NZ;
    static_assert(NWG % 8 == 0, "XCD swizzle needs nwg % 8 == 0");
    alignas(16) __shared__ u16 As[4 * 8192];
    alignas(16) __shared__ u16 Bs[4 * 8192];

    const int tid = threadIdx.x;
    const int lane = tid & 63, wave = tid >> 6;
    const int l16 = lane & 15, quad = lane >> 4;
    const int wm = wave >> 2;              // 0..1  (M)
    const int wn = wave & 3;               // 0..3  (N)

    const int lin = blockIdx.x;
    const int tl = (lin & 7) * (NWG / 8) + (lin >> 3);
    const int xe = tl % NX;
    const int ye = (tl / NX) % NY;
    const int zb = tl / (NX * NY);
    const long m0 = (long)ye * 256;
    const long n0 = (long)xe * 256;

    const u16* Aop = A + (long)zb * Asb;
    const u16* Bop = B + (long)zb * Bsb;

    const int srow = tid >> 2;
    const int sq = (tid & 3) ^ ((tid >> 3) & 3);
    const long gaofs0 = (m0 + srow) * lda + sq * 8;
    const long gaofs1 = gaofs0 + 128 * lda;
    const long gbofs0 = (n0 + srow) * ldb + sq * 8;
    const long gbofs1 = gbofs0 + 128 * ldb;
    const int wv512n = wave * 512;

    const int swzE = (quad ^ ((l16 >> 1) & 3)) * 8;
    const int aRow = (wm * 128 + l16) * 32 + swzE;
    const int bRow = (wn * 64 + l16) * 32 + swzE;

    v4f acc[8][4];
#pragma unroll
    for (int i = 0; i < 8; ++i)
#pragma unroll
        for (int j = 0; j < 4; ++j)
            acc[i][j] = (v4f){0.f, 0.f, 0.f, 0.f};
    v8h af[4];
    v8h bfr[2][4];

#define STAGE_A(RIDX, KP) do { \
        u16* lb_ = As + (RIDX) * 8192 + wv512n; \
        gload_lds16(Aop + gaofs0 + (KP), lb_); \
        gload_lds16(Aop + gaofs1 + (KP), lb_ + 4096); } while (0)
#define STAGE_B(RIDX, KP) do { \
        u16* lb_ = Bs + (RIDX) * 8192 + wv512n; \
        gload_lds16(Bop + gbofs0 + (KP), lb_); \
        gload_lds16(Bop + gbofs1 + (KP), lb_ + 4096); } while (0)

#define MF4(CH, I, BC) \
    acc[(CH)*4+(I)][0] = __builtin_amdgcn_mfma_f32_16x16x32_f16(af[I], bfr[BC][0], acc[(CH)*4+(I)][0], 0, 0, 0); \
    acc[(CH)*4+(I)][1] = __builtin_amdgcn_mfma_f32_16x16x32_f16(af[I], bfr[BC][1], acc[(CH)*4+(I)][1], 0, 0, 0); \
    acc[(CH)*4+(I)][2] = __builtin_amdgcn_mfma_f32_16x16x32_f16(af[I], bfr[BC][2], acc[(CH)*4+(I)][2], 0, 0, 0); \
    acc[(CH)*4+(I)][3] = __builtin_amdgcn_mfma_f32_16x16x32_f16(af[I], bfr[BC][3], acc[(CH)*4+(I)][3], 0, 0, 0);

#define PHASE(CH, BC, NRD, NCH, BLN, BN, ODD, STG) { \
        STG; \
        __builtin_amdgcn_s_setprio(1); \
        MF4(CH, 0, BC) \
        MF4(CH, 1, BC) \
        { const u16* Ar_ = As + (NRD) * 8192 + aRow + (NCH) * 2048; \
          af[0] = *(const v8h*)(Ar_); \
          af[1] = *(const v8h*)(Ar_ + 512); \
          if (BLN) { const u16* Br_ = Bs + (NRD) * 8192 + bRow; \
            bfr[BN][0] = *(const v8h*)(Br_); \
            bfr[BN][1] = *(const v8h*)(Br_ + 512); \
            bfr[BN][2] = *(const v8h*)(Br_ + 1024); \
            bfr[BN][3] = *(const v8h*)(Br_ + 1536); } } \
        MF4(CH, 2, BC) \
        { const u16* Ar_ = As + (NRD) * 8192 + aRow + (NCH) * 2048; \
          af[2] = *(const v8h*)(Ar_ + 1024); } \
        MF4(CH, 3, BC) \
        { const u16* Ar_ = As + (NRD) * 8192 + aRow + (NCH) * 2048; \
          af[3] = *(const v8h*)(Ar_ + 1536); } \
        __builtin_amdgcn_s_setprio(0); \
        if (ODD) asm volatile("s_waitcnt vmcnt(6)" ::: "memory"); \
        __builtin_amdgcn_s_barrier(); \
    }

    // prologue: regions r0,r1,r2 (12 loads); r0 resident after vmcnt(8)
    STAGE_A(0, 0);  STAGE_B(0, 0);
    STAGE_A(1, 32); STAGE_B(1, 32);
    STAGE_A(2, 64); STAGE_B(2, 64);
    asm volatile("s_waitcnt vmcnt(8)" ::: "memory");
    __builtin_amdgcn_s_barrier();

    // pre-loop fragment reads: r0 / CH0 (A) + r0 (B bank0)
#pragma unroll
    for (int i = 0; i < 4; ++i) af[i] = *(const v8h*)&As[aRow + i * 512];
#pragma unroll
    for (int j = 0; j < 4; ++j) bfr[0][j] = *(const v8h*)&Bs[bRow + j * 512];

    const int NT = K >> 7;   // K % 128 == 0
#pragma unroll 1
    for (int t = 0; t < NT; ++t) {
        const long kb = (long)t * 128;
        const long kp1 = kb + 96;
        long kp2  = kb + 128; if (kp2  >= K) kp2  = 0;
        long kp2b = kb + 160; if (kp2b >= K) kp2b = 0;
        long kp3  = kb + 192; if (kp3  >= K) kp3  = 0;

        //    CH BC  NRD NCH BLN BN ODD  stage
        PHASE(0, 0,  0,  1,  0, 0, 1, STAGE_A(3, kp1))   // W1: r0/CH0; rd r0/CH1
        PHASE(1, 0,  1,  0,  1, 1, 0, STAGE_B(3, kp1))   // W2: r0/CH1; rd r1/CH0 + B1
        PHASE(0, 1,  1,  1,  0, 0, 1, STAGE_A(0, kp2))   // W3: r1/CH0; rd r1/CH1
        PHASE(1, 1,  2,  0,  1, 0, 0, STAGE_B(0, kp2))   // W4: r1/CH1; rd r2/CH0 + B0
        PHASE(0, 0,  2,  1,  0, 0, 1, STAGE_A(1, kp2b))  // W5: r2/CH0; rd r2/CH1
        PHASE(1, 0,  3,  0,  1, 1, 0, STAGE_B(1, kp2b))  // W6: r2/CH1; rd r3/CH0 + B1
        PHASE(0, 1,  3,  1,  0, 0, 1, STAGE_A(2, kp3))   // W7: r3/CH0; rd r3/CH1
        PHASE(1, 1,  0,  0,  1, 0, 0, STAGE_B(2, kp3))   // W8: r3/CH1; rd r0/CH0 + B0
    }

    // hardened: drain all outstanding DMA/LDS ops before epilogue/endpgm
    asm volatile("s_waitcnt vmcnt(0) lgkmcnt(0)" ::: "memory");
    __builtin_amdgcn_s_barrier();

#undef PHASE
#undef MF4
#undef STAGE_A
#undef STAGE_B

    float bv[4];
#pragma unroll
    for (int j = 0; j < 4; ++j) {
        const long col = n0 + wn * 64 + j * 16 + l16;
        if (BIAS == 0) bv[j] = 0.f;
        else if (BIAS == 1) bv[j] = bias[col];
        else {
            const int sel = (int)(col >> 10);
            const float* bp = sel == 0 ? bias : (sel == 1 ? bias2 : bias3);
            bv[j] = bp[col & 1023];
        }
    }

    if (OMODE == 3 && n0 >= 2048) {
        const long bb = m0 >> 11, mb = m0 & 2047;
        u16* C = C1 + bb * Csb;
#pragma unroll
        for (int j = 0; j < 4; ++j) {
            const long col = n0 - 2048 + wn * 64 + j * 16 + l16;
            u16* pc = C + col * 2048 + mb + wm * 128 + quad * 4;
#pragma unroll
            for (int i = 0; i < 8; ++i) {
                u16 o[4];
#pragma unroll
                for (int r = 0; r < 4; ++r) {
                    float val = acc[i][j][r] + bv[j];
                    if (RELU) val = fmaxf(val, 0.f);
                    o[r] = f2h(val);
                }
                *(uint2*)(pc + i * 16) = *(const uint2*)o;
            }
        }
    } else {
        const long cb = (OMODE == 3 ? 0 : (long)zb * Csb)
                      + (m0 + wm * 128 + quad * 4) * ldc + (n0 + wn * 64 + l16);
        u16* p0 = (u16*)Cv + cb;
#pragma unroll
        for (int i = 0; i < 8; ++i)
#pragma unroll
            for (int r = 0; r < 4; ++r) {
                u16* prow = p0 + (long)(i * 16 + r) * ldc;
#pragma unroll
                for (int j = 0; j < 4; ++j) {
                    float val = acc[i][j][r] + bv[j];
                    if (RELU) val = fmaxf(val, 0.f);
                    prow[j * 16] = f2h(val);
                }
            }
    }
}

// ======== 256x128 8-phase f16 GEMM, 4Mx2N wave grid (per-wave 64x64) ========
// NEW vs round-2/4: (1) wave grid 4M x 2N -> per-wave 64x64 output
// (acc[4][4]); per-wave LDS reads drop 20->16 b128/K-tile -> MfmaUtil
// ratio-ceiling 48% -> 60%. (2) LDS 80 KiB: 4 A-regions [256][32] +
// 2 B-slots [128][32] (slot = K-half parity, ping-pong) -> 2 blocks/CU
// possible where grid > 256 (QKV).  __launch_bounds__(512,4) caps VGPR<=128.
// Wait derivation (2-slot B, stage order A3|Bs0|A0|Bs1|A1|Bs0|A2|Bs1):
//   B staged at even windows with 3-window lead; deadline analysis ->
//   vmcnt(2) at even-window TOPS (leaves only prior odd window's 2 A-loads).
//   Prologue 8 loads (A0,B0,A1,B1,A2), vmcnt(5) leaves A1,B1,A2.
//   Cross-wave residency: every wave executes the same vmcnt, then two
//   barriers sit between wait and use. Slot-overwrite WAR: reads of a
//   region drain (per-wave lgkmcnt(0) before MFMA) before that window's
//   trailing barrier; stage happens after it.
//   B stages never need k-clamp (kb+96 <= K-32); A clamped as before.
// k-summation order per output element unchanged -> bit-identical results.
template<int OMODE, int BIAS, bool RELU, int NX, int NY, int NZ>
__global__ __launch_bounds__(512, 4) void gemm256n(
    const u16* __restrict__ A, long lda, long Asb,
    const u16* __restrict__ B, long ldb, long Bsb,
    void* __restrict__ Cv, long ldc, long Csb, u16* __restrict__ C1,
    const float* __restrict__ bias, const float* __restrict__ bias2,
    const float* __restrict__ bias3, int K)
{
    constexpr int NWG = NX * NY * NZ;
    static_assert(NWG % 8 == 0, "XCD swizzle needs nwg % 8 == 0");
    alignas(16) __shared__ u16 As[4 * 8192];   // 64 KiB: 4 regions [256][32]
    alignas(16) __shared__ u16 Bs[2 * 4096];   // 16 KiB: 2 slots [128][32]

    const int tid = threadIdx.x;
    const int lane = tid & 63, wave = tid >> 6;
    const int l16 = lane & 15, quad = lane >> 4;
    const int wm = wave >> 1;              // 0..3 (M, 64 rows each)
    const int wn = wave & 1;               // 0..1 (N, 64 cols each)

    const int lin = blockIdx.x;
    const int tl = (lin & 7) * (NWG / 8) + (lin >> 3);
    const int xe = tl % NX;
    const int ye = (tl / NX) % NY;
    const int zb = tl / (NX * NY);
    const long m0 = (long)ye * 256;
    const long n0 = (long)xe * 128;

    const u16* Aop = A + (long)zb * Asb;
    const u16* Bop = B + (long)zb * Bsb;

    const int srow = tid >> 2;                       // 0..127
    const int sq = (tid & 3) ^ ((tid >> 3) & 3);
    const long gaofs0 = (m0 + srow) * lda + sq * 8;
    const long gaofs1 = gaofs0 + 128 * lda;
    const long gbofs0 = (n0 + srow) * ldb + sq * 8;  // B region = 128 rows
    const int wv512n = wave * 512;

    const int swzE = (quad ^ ((l16 >> 1) & 3)) * 8;
    const int aRow = (wm * 64 + l16) * 32 + swzE;
    const int bRow = (wn * 64 + l16) * 32 + swzE;

    v4f acc[4][4];
#pragma unroll
    for (int i = 0; i < 4; ++i)
#pragma unroll
        for (int j = 0; j < 4; ++j)
            acc[i][j] = (v4f){0.f, 0.f, 0.f, 0.f};
    v8h bf[4];

#define STAGE_A(RIDX, KP) do { \
        u16* lb_ = As + (RIDX) * 8192 + wv512n; \
        gload_lds16(Aop + gaofs0 + (KP), lb_); \
        gload_lds16(Aop + gaofs1 + (KP), lb_ + 4096); } while (0)
#define STAGE_B(SLOT, KP) do { \
        gload_lds16(Bop + gbofs0 + (KP), Bs + (SLOT) * 4096 + wv512n); } while (0)

#define PHASE(BUF, KH, CH, EVENW, STG) { \
        if (EVENW) asm volatile("s_waitcnt vmcnt(2)" ::: "memory"); \
        const u16* Ar_ = As + ((BUF) * 2 + (KH)) * 8192 + aRow + (CH) * 1024; \
        v8h af0 = *(const v8h*)(Ar_); \
        v8h af1 = *(const v8h*)(Ar_ + 512); \
        if ((CH) == 0) { \
            const u16* Br_ = Bs + (KH) * 4096 + bRow; \
            bf[0] = *(const v8h*)(Br_); \
            bf[1] = *(const v8h*)(Br_ + 512); \
            bf[2] = *(const v8h*)(Br_ + 1024); \
            bf[3] = *(const v8h*)(Br_ + 1536); \
        } \
        STG; \
        __builtin_amdgcn_s_barrier(); \
        asm volatile("s_waitcnt lgkmcnt(0)" ::: "memory"); \
        __builtin_amdgcn_s_setprio(1); \
        acc[(CH)*2+0][0] = __builtin_amdgcn_mfma_f32_16x16x32_f16(af0, bf[0], acc[(CH)*2+0][0], 0, 0, 0); \
        acc[(CH)*2+0][1] = __builtin_amdgcn_mfma_f32_16x16x32_f16(af0, bf[1], acc[(CH)*2+0][1], 0, 0, 0); \
        acc[(CH)*2+0][2] = __builtin_amdgcn_mfma_f32_16x16x32_f16(af0, bf[2], acc[(CH)*2+0][2], 0, 0, 0); \
        acc[(CH)*2+0][3] = __builtin_amdgcn_mfma_f32_16x16x32_f16(af0, bf[3], acc[(CH)*2+0][3], 0, 0, 0); \
        acc[(CH)*2+1][0] = __builtin_amdgcn_mfma_f32_16x16x32_f16(af1, bf[0], acc[(CH)*2+1][0], 0, 0, 0); \
        acc[(CH)*2+1][1] = __builtin_amdgcn_mfma_f32_16x16x32_f16(af1, bf[1], acc[(CH)*2+1][1], 0, 0, 0); \
        acc[(CH)*2+1][2] = __builtin_amdgcn_mfma_f32_16x16x32_f16(af1, bf[2], acc[(CH)*2+1][2], 0, 0, 0); \
        acc[(CH)*2+1][3] = __builtin_amdgcn_mfma_f32_16x16x32_f16(af1, bf[3], acc[(CH)*2+1][3], 0, 0, 0); \
        __builtin_amdgcn_s_setprio(0); \
        __builtin_amdgcn_s_barrier(); \
    }

    // prologue: A r0,r1,r2 + B slot0,slot1 (8 loads); vmcnt(5) leaves A1,B1,A2
    STAGE_A(0, 0);  STAGE_B(0, 0);
    STAGE_A(1, 32); STAGE_B(1, 32);
    STAGE_A(2, 64);
    asm volatile("s_waitcnt vmcnt(5)" ::: "memory");
    __builtin_amdgcn_s_barrier();

    const int NT = K >> 7;   // K % 128 == 0
#pragma unroll 1
    for (int t = 0; t < NT; ++t) {
        const long kb = (long)t * 128;
        long kp2  = kb + 128; if (kp2  >= K) kp2  = 0;
        long kp2b = kb + 160; if (kp2b >= K) kp2b = 0;
        long kp3  = kb + 192; if (kp3  >= K) kp3  = 0;

        PHASE(0, 0, 0, false, STAGE_A(3, kb + 96))   // P1: rd A-r0/CH0 + B-s0
        PHASE(0, 0, 1, true,  STAGE_B(0, kb + 64))   // P2: rd A-r0/CH1; s0 <- kb+64
        PHASE(0, 1, 0, false, STAGE_A(0, kp2))       // P3: rd A-r1/CH0 + B-s1
        PHASE(0, 1, 1, true,  STAGE_B(1, kb + 96))   // P4: rd A-r1/CH1; s1 <- kb+96
        PHASE(1, 0, 0, false, STAGE_A(1, kp2b))      // P5: rd A-r2/CH0 + B-s0
        PHASE(1, 0, 1, true,  STAGE_B(0, kp2))       // P6: rd A-r2/CH1; s0 <- kb+128
        PHASE(1, 1, 0, false, STAGE_A(2, kp3))       // P7: rd A-r3/CH0 + B-s1
        PHASE(1, 1, 1, true,  STAGE_B(1, kp2b))      // P8: rd A-r3/CH1; s1 <- kb+160
    }

    // hardened: drain all outstanding DMA/LDS ops before epilogue/endpgm
    asm volatile("s_waitcnt vmcnt(0) lgkmcnt(0)" ::: "memory");
    __builtin_amdgcn_s_barrier();

#undef PHASE
#undef STAGE_A
#undef STAGE_B

    float bv[4];
#pragma unroll
    for (int j = 0; j < 4; ++j) {
        const long col = n0 + wn * 64 + j * 16 + l16;
        if (BIAS == 0) bv[j] = 0.f;
        else if (BIAS == 1) bv[j] = bias[col];
        else {
            const int sel = (int)(col >> 10);
            const float* bp = sel == 0 ? bias : (sel == 1 ? bias2 : bias3);
            bv[j] = bp[col & 1023];
        }
    }

    if (OMODE == 3 && n0 >= 2048) {
        const long bb = m0 >> 11, mb = m0 & 2047;
        u16* C = C1 + bb * Csb;
#pragma unroll
        for (int j = 0; j < 4; ++j) {
            const long col = n0 - 2048 + wn * 64 + j * 16 + l16;
            u16* pc = C + col * 2048 + mb + wm * 64 + quad * 4;
#pragma unroll
            for (int i = 0; i < 4; ++i) {
                u16 o[4];
#pragma unroll
                for (int r = 0; r < 4; ++r) {
                    float val = acc[i][j][r] + bv[j];
                    if (RELU) val = fmaxf(val, 0.f);
                    o[r] = f2h(val);
                }
                *(uint2*)(pc + i * 16) = *(const uint2*)o;
            }
        }
    } else {
        const long cb = (OMODE == 3 ? 0 : (long)zb * Csb)
                      + (m0 + wm * 64 + quad * 4) * ldc + (n0 + wn * 64 + l16);
        u16* p0 = (u16*)Cv + cb;
#pragma unroll
        for (int i = 0; i < 4; ++i)
#pragma unroll
            for (int r = 0; r < 4; ++r) {
                u16* prow = p0 + (long)(i * 16 + r) * ldc;
#pragma unroll
                for (int j = 0; j < 4; ++j) {
                    float val = acc[i][j][r] + bv[j];
                    if (RELU) val = fmaxf(val, 0.f);
                    prow[j * 16] = f2h(val);
                }
            }
    }
}

// ---------------- softmax over f16 rows of 2048, in place ----------------
__global__ __launch_bounds__(256) void softmax_rows(u16* __restrict__ S) {
    const long row = blockIdx.x;
    u16* p = S + row * 2048;
    const int t = threadIdx.x;
    float v[8];
    float mx = -1e30f;
#pragma unroll
    for (int i = 0; i < 8; ++i) { v[i] = h2f(p[t + i * 256]); mx = fmaxf(mx, v[i]); }
    __shared__ float red[256];
    red[t] = mx; __syncthreads();
    for (int off = 128; off > 0; off >>= 1) {
        if (t < off) red[t] = fmaxf(red[t], red[t + off]);
        __syncthreads();
    }
    mx = red[0]; __syncthreads();
    float sum = 0.f;
#pragma unroll
    for (int i = 0; i < 8; ++i) { v[i] = __expf(v[i] - mx); sum += v[i]; }
    red[t] = sum; __syncthreads();
    for (int off = 128; off > 0; off >>= 1) {
        if (t < off) red[t] += red[t + off];
        __syncthreads();
    }
    const float inv = 1.f / red[0];
#pragma unroll
    for (int i = 0; i < 8; ++i) p[t + i * 256] = f2h(v[i] * inv);
}

// ---------------- ln1: xh_f16 = LN(src_f32 + attnO_f16) ----------------
__global__ __launch_bounds__(256) void ln_one(
    const float* __restrict__ a, const u16* __restrict__ bb,
    const float* __restrict__ g, const float* __restrict__ be,
    u16* __restrict__ out16)
{
    const long base = (long)blockIdx.x * 1024;
    const int t = threadIdx.x;
    float v[4]; float s = 0.f, ss = 0.f;
#pragma unroll
    for (int i = 0; i < 4; ++i) {
        const int c = t + i * 256;
        const float x = a[base + c] + h2f(bb[base + c]);
        v[i] = x; s += x; ss += x * x;
    }
    __shared__ float rs[256], rss[256];
    rs[t] = s; rss[t] = ss; __syncthreads();
    for (int off = 128; off > 0; off >>= 1) {
        if (t < off) { rs[t] += rs[t + off]; rss[t] += rss[t + off]; }
        __syncthreads();
    }
    const float mean = rs[0] * (1.f / 1024.f);
    const float var = rss[0] * (1.f / 1024.f) - mean * mean;
    const float rstd = rsqrtf(var + 1e-5f);
#pragma unroll
    for (int i = 0; i < 4; ++i) {
        const int c = t + i * 256;
        out16[base + c] = f2h((v[i] - mean) * rstd * g[c] + be[c]);
    }
}

// ---------------- ln2: out_f32 = LN(xh_f16 + ffO_f16) ----------------
__global__ __launch_bounds__(256) void ln_two(
    const u16* __restrict__ a, const u16* __restrict__ bb,
    const float* __restrict__ g, const float* __restrict__ be,
    float* __restrict__ out)
{
    const long base = (long)blockIdx.x * 1024;
    const int t = threadIdx.x;
    float v[4]; float s = 0.f, ss = 0.f;
#pragma unroll
    for (int i = 0; i < 4; ++i) {
        const int c = t + i * 256;
        const float x = h2f(a[base + c]) + h2f(bb[base + c]);
        v[i] = x; s += x; ss += x * x;
    }
    __shared__ float rs[256], rss[256];
    rs[t] = s; rss[t] = ss; __syncthreads();
    for (int off = 128; off > 0; off >>= 1) {
        if (t < off) { rs[t] += rs[t + off]; rss[t] += rss[t + off]; }
        __syncthreads();
    }
    const float mean = rs[0] * (1.f / 1024.f);
    const float var = rss[0] * (1.f / 1024.f) - mean * mean;
    const float rstd = rsqrtf(var + 1e-5f);
#pragma unroll
    for (int i = 0; i < 4; ++i) {
        const int c = t + i * 256;
        out[base + c] = (v[i] - mean) * rstd * g[c] + be[c];
    }
}

extern "C" void kernel_launch(void* const* d_in, const int* in_sizes, int n_in,
                              void* d_out, int out_size, void* d_ws, size_t ws_size,
                              hipStream_t stream) {
    (void)in_sizes; (void)n_in; (void)out_size; (void)ws_size;
    constexpr long S = 2048, E = 1024, F = 4096, M = 8192;

    const float* src = (const float*)d_in[0];
    const float* Wq  = (const float*)d_in[1];
    const float* bq  = (const float*)d_in[2];
    const float* Wk  = (const float*)d_in[3];
    const float* bk  = (const float*)d_in[4];
    const float* Wv  = (const float*)d_in[5];
    const float* bv  = (const float*)d_in[6];
    const float* Wo  = (const float*)d_in[7];
    const float* bo  = (const float*)d_in[8];
    const float* W1  = (const float*)d_in[9];
    const float* b1  = (const float*)d_in[10];
    const float* W2  = (const float*)d_in[11];
    const float* b2  = (const float*)d_in[12];
    const float* g1  = (const float*)d_in[13];
    const float* be1 = (const float*)d_in[14];
    const float* g2  = (const float*)d_in[15];
    const float* be2 = (const float*)d_in[16];

    char* ws = (char*)d_ws;
    size_t off = 0;
    auto take = [&](size_t bytes) {
        char* p = ws + off;
        off += (bytes + 255) & ~(size_t)255;
        return p;
    };
    const size_t MB16 = 16777216;  // f16 [8192][1024]
    u16*   srcH  = (u16*)take(MB16);
    u16*   WqkvT = (u16*)take(3 * E * E * 2);     // [3072][1024]: WqT | WkT | WvT
    u16*   WoT   = (u16*)take(E * E * 2);
    u16*   W1T   = (u16*)take(F * E * 2);         // [4096][1024]
    u16*   W2T   = (u16*)take(E * F * 2);         // [1024][4096]
    char*  B0    = take(2 * MB16);                // QK f16 [8192][2048]
    char*  B1    = take(MB16);                    // VT f16 [4][1024][2048]
    char*  B2    = take(4ull * S * S * 4);        // Sh f16 (32M) -> hf f16 [8192][4096] (64M)
    char*  B3    = take(MB16);                    // attn f16 -> xh f16
    char*  B4    = take(MB16);                    // attnO f16 -> ffO f16

    u16*   QK    = (u16*)B0;
    u16*   VT    = (u16*)B1;
    u16*   Sh    = (u16*)B2;
    u16*   hf    = (u16*)B2;
    u16*   attn  = (u16*)B3;
    u16*   xh    = (u16*)B3;
    u16*   attnO = (u16*)B4;
    u16*   ffO   = (u16*)B4;

    dim3 blk(256), blk5(512), tb(32, 8);

    // 1) convert src -> f16
    cvt_f16<<<dim3(M * E / 8 / 256), blk, 0, stream>>>(src, srcH, M * E / 8);

    // 2) all weight transposes in one launch
    transpose_all<<<dim3(12288), tb, 0, stream>>>(Wq, Wk, Wv, Wo, W1, W2,
                                                  WqkvT, WoT, W1T, W2T);

    // 3) merged Q|K|V projection (256x128 4Mx2N): 768 blocks (2/CU capable)
    gemm256n<3, 3, false, 24, 32, 1><<<dim3(24 * 32), blk5, 0, stream>>>(
        srcH, E, 0, WqkvT, E, 0, QK, 2 * E, E * S, VT, bq, bk, bv, E);

    // 4) scores[b] = Q[b] @ K[b]^T (256x256 OVERLAPPED, 256 blocks)
    gemm256<0, 0, false, 8, 8, 4><<<dim3(8 * 8 * 4), blk5, 0, stream>>>(
        QK, 2 * E, S * 2 * E, QK + E, 2 * E, S * 2 * E,
        Sh, S, S * S, nullptr, nullptr, nullptr, nullptr, E);

    // 5) softmax in place (f16)
    softmax_rows<<<dim3(M), blk, 0, stream>>>(Sh);

    // 6) attn[b] = P[b] @ V[b] (256x128 4Mx2N, 256 blocks)
    gemm256n<0, 0, false, 8, 8, 4><<<dim3(8 * 8 * 4), blk5, 0, stream>>>(
        Sh, S, S * S, VT, S, E * S,
        attn, E, S * E, nullptr, nullptr, nullptr, nullptr, S);

    // 7) attnO = attn @ Wo + bo (256x128 4Mx2N, 256 blocks)
    gemm256n<0, 1, false, 8, 32, 1><<<dim3(8 * 32), blk5, 0, stream>>>(
        attn, E, 0, WoT, E, 0, attnO, E, 0, nullptr, bo, nullptr, nullptr, E);

    // 8) xh = LN(src + attnO) (f16, over dead attn)
    ln_one<<<dim3(M), blk, 0, stream>>>(src, attnO, g1, be1, xh);

    // 9) hf = relu(xh @ W1 + b1) (256x256 OVERLAPPED, 512 blocks)
    gemm256<0, 1, true, 16, 32, 1><<<dim3(16 * 32), blk5, 0, stream>>>(
        xh, E, 0, W1T, E, 0, hf, F, 0, nullptr, b1, nullptr, nullptr, E);

    // 10) ffO = hf @ W2 + b2 (256x128 4Mx2N, 256 blocks, K=4096)
    gemm256n<0, 1, false, 8, 32, 1><<<dim3(8 * 32), blk5, 0, stream>>>(
        hf, F, 0, W2T, F, 0, ffO, E, 0, nullptr, b2, nullptr, nullptr, F);

    // 11) out = LN(xh + ffO) -> f32
    ln_two<<<dim3(M), blk, 0, stream>>>(xh, ffO, g2, be2, (float*)d_out);
}

// Round 6
// 496.172 us; speedup vs baseline: 1.1256x; 1.0060x over previous
//
#include <hip/hip_runtime.h>
#include <stdint.h>

typedef unsigned short u16;
typedef _Float16 v8h __attribute__((ext_vector_type(8)));
typedef float v4f __attribute__((ext_vector_type(4)));

static __device__ __forceinline__ float h2f(u16 u) {
    union { u16 s; _Float16 h; } v; v.s = u; return (float)v.h;
}
static __device__ __forceinline__ u16 f2h(float f) {
    union { u16 s; _Float16 h; } v; v.h = (_Float16)f; return v.s;
}

// async global->LDS, 16B per lane. lds dest = wave-uniform base + lane*16.
static __device__ __forceinline__ void gload_lds16(const u16* g, const u16* l) {
    __builtin_amdgcn_global_load_lds(
        (const __attribute__((address_space(1))) uint32_t*)(uintptr_t)g,
        (__attribute__((address_space(3))) uint32_t*)(uintptr_t)l,
        16, 0, 0);
}

// ---------------- convert f32 -> f16, vectorized x8 ----------------
__global__ __launch_bounds__(256) void cvt_f16(const float* __restrict__ in,
                                               u16* __restrict__ out, int n8) {
    const int i = blockIdx.x * 256 + threadIdx.x;
    if (i >= n8) return;
    const float4 a = ((const float4*)in)[2 * i];
    const float4 b = ((const float4*)in)[2 * i + 1];
    u16 o[8] = {f2h(a.x), f2h(a.y), f2h(a.z), f2h(a.w),
                f2h(b.x), f2h(b.y), f2h(b.z), f2h(b.w)};
    *(uint4*)(out + (size_t)i * 8) = *(const uint4*)o;
}

// ---------------- all weight transposes f32 [R][C] -> f16 [C][R], one launch ----------------
__global__ __launch_bounds__(256) void transpose_all(
    const float* __restrict__ Wq, const float* __restrict__ Wk,
    const float* __restrict__ Wv, const float* __restrict__ Wo,
    const float* __restrict__ W1, const float* __restrict__ W2,
    u16* __restrict__ WqkvT, u16* __restrict__ WoT,
    u16* __restrict__ W1T, u16* __restrict__ W2T)
{
    int t = blockIdx.x;
    const float* in; u16* out; long ldi, ldo; int xt;
    if (t < 1024)      {            in = Wq; out = WqkvT;               ldi = 1024; ldo = 1024; xt = 32; }
    else if (t < 2048) { t -= 1024; in = Wk; out = WqkvT + 1024*1024;   ldi = 1024; ldo = 1024; xt = 32; }
    else if (t < 3072) { t -= 2048; in = Wv; out = WqkvT + 2*1024*1024; ldi = 1024; ldo = 1024; xt = 32; }
    else if (t < 4096) { t -= 3072; in = Wo; out = WoT;                 ldi = 1024; ldo = 1024; xt = 32; }
    else if (t < 8192) { t -= 4096; in = W1; out = W1T;                 ldi = 4096; ldo = 1024; xt = 128; }
    else               { t -= 8192; in = W2; out = W2T;                 ldi = 1024; ldo = 4096; xt = 32; }
    const int c0 = (t % xt) * 32, r0 = (t / xt) * 32;
    __shared__ float tile[32][33];
    for (int i = threadIdx.y; i < 32; i += 8)
        tile[i][threadIdx.x] = in[(long)(r0 + i) * ldi + c0 + threadIdx.x];
    __syncthreads();
    for (int i = threadIdx.y; i < 32; i += 8)
        out[(long)(c0 + i) * ldo + r0 + threadIdx.x] = f2h(tile[threadIdx.x][i]);
}

// ======== 256x128 8-phase f16 GEMM, 4Mx2N wave grid (per-wave 64x64) ========
// r5-proven kernel, now the ONLY GEMM (block-TLP round): 80 KiB LDS ->
// TWO blocks co-resident per CU (160 KiB exactly) wherever grid >= 512.
// Rationale: three intra-block schedule variants all capped MfmaUtil at
// 37-40% with 1 block/CU -> per-phase latencies (DMA arrival, barrier
// reconvergence) are exposed; a second resident block masks them (m114
// mechanism). Schedule, waits, and k-order UNCHANGED from r5 (proven).
template<int OMODE, int BIAS, bool RELU, int NX, int NY, int NZ>
__global__ __launch_bounds__(512, 4) void gemm256n(
    const u16* __restrict__ A, long lda, long Asb,
    const u16* __restrict__ B, long ldb, long Bsb,
    void* __restrict__ Cv, long ldc, long Csb, u16* __restrict__ C1,
    const float* __restrict__ bias, const float* __restrict__ bias2,
    const float* __restrict__ bias3, int K)
{
    constexpr int NWG = NX * NY * NZ;
    static_assert(NWG % 8 == 0, "XCD swizzle needs nwg % 8 == 0");
    alignas(16) __shared__ u16 As[4 * 8192];   // 64 KiB: 4 regions [256][32]
    alignas(16) __shared__ u16 Bs[2 * 4096];   // 16 KiB: 2 slots [128][32]

    const int tid = threadIdx.x;
    const int lane = tid & 63, wave = tid >> 6;
    const int l16 = lane & 15, quad = lane >> 4;
    const int wm = wave >> 1;              // 0..3 (M, 64 rows each)
    const int wn = wave & 1;               // 0..1 (N, 64 cols each)

    const int lin = blockIdx.x;
    const int tl = (lin & 7) * (NWG / 8) + (lin >> 3);
    const int xe = tl % NX;
    const int ye = (tl / NX) % NY;
    const int zb = tl / (NX * NY);
    const long m0 = (long)ye * 256;
    const long n0 = (long)xe * 128;

    const u16* Aop = A + (long)zb * Asb;
    const u16* Bop = B + (long)zb * Bsb;

    const int srow = tid >> 2;                       // 0..127
    const int sq = (tid & 3) ^ ((tid >> 3) & 3);
    const long gaofs0 = (m0 + srow) * lda + sq * 8;
    const long gaofs1 = gaofs0 + 128 * lda;
    const long gbofs0 = (n0 + srow) * ldb + sq * 8;  // B region = 128 rows
    const int wv512n = wave * 512;

    const int swzE = (quad ^ ((l16 >> 1) & 3)) * 8;
    const int aRow = (wm * 64 + l16) * 32 + swzE;
    const int bRow = (wn * 64 + l16) * 32 + swzE;

    v4f acc[4][4];
#pragma unroll
    for (int i = 0; i < 4; ++i)
#pragma unroll
        for (int j = 0; j < 4; ++j)
            acc[i][j] = (v4f){0.f, 0.f, 0.f, 0.f};
    v8h bf[4];

#define STAGE_A(RIDX, KP) do { \
        u16* lb_ = As + (RIDX) * 8192 + wv512n; \
        gload_lds16(Aop + gaofs0 + (KP), lb_); \
        gload_lds16(Aop + gaofs1 + (KP), lb_ + 4096); } while (0)
#define STAGE_B(SLOT, KP) do { \
        gload_lds16(Bop + gbofs0 + (KP), Bs + (SLOT) * 4096 + wv512n); } while (0)

#define PHASE(BUF, KH, CH, EVENW, STG) { \
        if (EVENW) asm volatile("s_waitcnt vmcnt(2)" ::: "memory"); \
        const u16* Ar_ = As + ((BUF) * 2 + (KH)) * 8192 + aRow + (CH) * 1024; \
        v8h af0 = *(const v8h*)(Ar_); \
        v8h af1 = *(const v8h*)(Ar_ + 512); \
        if ((CH) == 0) { \
            const u16* Br_ = Bs + (KH) * 4096 + bRow; \
            bf[0] = *(const v8h*)(Br_); \
            bf[1] = *(const v8h*)(Br_ + 512); \
            bf[2] = *(const v8h*)(Br_ + 1024); \
            bf[3] = *(const v8h*)(Br_ + 1536); \
        } \
        STG; \
        __builtin_amdgcn_s_barrier(); \
        asm volatile("s_waitcnt lgkmcnt(0)" ::: "memory"); \
        __builtin_amdgcn_s_setprio(1); \
        acc[(CH)*2+0][0] = __builtin_amdgcn_mfma_f32_16x16x32_f16(af0, bf[0], acc[(CH)*2+0][0], 0, 0, 0); \
        acc[(CH)*2+0][1] = __builtin_amdgcn_mfma_f32_16x16x32_f16(af0, bf[1], acc[(CH)*2+0][1], 0, 0, 0); \
        acc[(CH)*2+0][2] = __builtin_amdgcn_mfma_f32_16x16x32_f16(af0, bf[2], acc[(CH)*2+0][2], 0, 0, 0); \
        acc[(CH)*2+0][3] = __builtin_amdgcn_mfma_f32_16x16x32_f16(af0, bf[3], acc[(CH)*2+0][3], 0, 0, 0); \
        acc[(CH)*2+1][0] = __builtin_amdgcn_mfma_f32_16x16x32_f16(af1, bf[0], acc[(CH)*2+1][0], 0, 0, 0); \
        acc[(CH)*2+1][1] = __builtin_amdgcn_mfma_f32_16x16x32_f16(af1, bf[1], acc[(CH)*2+1][1], 0, 0, 0); \
        acc[(CH)*2+1][2] = __builtin_amdgcn_mfma_f32_16x16x32_f16(af1, bf[2], acc[(CH)*2+1][2], 0, 0, 0); \
        acc[(CH)*2+1][3] = __builtin_amdgcn_mfma_f32_16x16x32_f16(af1, bf[3], acc[(CH)*2+1][3], 0, 0, 0); \
        __builtin_amdgcn_s_setprio(0); \
        __builtin_amdgcn_s_barrier(); \
    }

    // prologue: A r0,r1,r2 + B slot0,slot1 (8 loads); vmcnt(5) leaves A1,B1,A2
    STAGE_A(0, 0);  STAGE_B(0, 0);
    STAGE_A(1, 32); STAGE_B(1, 32);
    STAGE_A(2, 64);
    asm volatile("s_waitcnt vmcnt(5)" ::: "memory");
    __builtin_amdgcn_s_barrier();

    const int NT = K >> 7;   // K % 128 == 0
#pragma unroll 1
    for (int t = 0; t < NT; ++t) {
        const long kb = (long)t * 128;
        long kp2  = kb + 128; if (kp2  >= K) kp2  = 0;
        long kp2b = kb + 160; if (kp2b >= K) kp2b = 0;
        long kp3  = kb + 192; if (kp3  >= K) kp3  = 0;

        PHASE(0, 0, 0, false, STAGE_A(3, kb + 96))   // P1: rd A-r0/CH0 + B-s0
        PHASE(0, 0, 1, true,  STAGE_B(0, kb + 64))   // P2: rd A-r0/CH1; s0 <- kb+64
        PHASE(0, 1, 0, false, STAGE_A(0, kp2))       // P3: rd A-r1/CH0 + B-s1
        PHASE(0, 1, 1, true,  STAGE_B(1, kb + 96))   // P4: rd A-r1/CH1; s1 <- kb+96
        PHASE(1, 0, 0, false, STAGE_A(1, kp2b))      // P5: rd A-r2/CH0 + B-s0
        PHASE(1, 0, 1, true,  STAGE_B(0, kp2))       // P6: rd A-r2/CH1; s0 <- kb+128
        PHASE(1, 1, 0, false, STAGE_A(2, kp3))       // P7: rd A-r3/CH0 + B-s1
        PHASE(1, 1, 1, true,  STAGE_B(1, kp2b))      // P8: rd A-r3/CH1; s1 <- kb+160
    }

    // hardened: drain all outstanding DMA/LDS ops before epilogue/endpgm
    asm volatile("s_waitcnt vmcnt(0) lgkmcnt(0)" ::: "memory");
    __builtin_amdgcn_s_barrier();

#undef PHASE
#undef STAGE_A
#undef STAGE_B

    float bv[4];
#pragma unroll
    for (int j = 0; j < 4; ++j) {
        const long col = n0 + wn * 64 + j * 16 + l16;
        if (BIAS == 0) bv[j] = 0.f;
        else if (BIAS == 1) bv[j] = bias[col];
        else {
            const int sel = (int)(col >> 10);
            const float* bp = sel == 0 ? bias : (sel == 1 ? bias2 : bias3);
            bv[j] = bp[col & 1023];
        }
    }

    if (OMODE == 3 && n0 >= 2048) {
        const long bb = m0 >> 11, mb = m0 & 2047;
        u16* C = C1 + bb * Csb;
#pragma unroll
        for (int j = 0; j < 4; ++j) {
            const long col = n0 - 2048 + wn * 64 + j * 16 + l16;
            u16* pc = C + col * 2048 + mb + wm * 64 + quad * 4;
#pragma unroll
            for (int i = 0; i < 4; ++i) {
                u16 o[4];
#pragma unroll
                for (int r = 0; r < 4; ++r) {
                    float val = acc[i][j][r] + bv[j];
                    if (RELU) val = fmaxf(val, 0.f);
                    o[r] = f2h(val);
                }
                *(uint2*)(pc + i * 16) = *(const uint2*)o;
            }
        }
    } else {
        const long cb = (OMODE == 3 ? 0 : (long)zb * Csb)
                      + (m0 + wm * 64 + quad * 4) * ldc + (n0 + wn * 64 + l16);
        u16* p0 = (u16*)Cv + cb;
#pragma unroll
        for (int i = 0; i < 4; ++i)
#pragma unroll
            for (int r = 0; r < 4; ++r) {
                u16* prow = p0 + (long)(i * 16 + r) * ldc;
#pragma unroll
                for (int j = 0; j < 4; ++j) {
                    float val = acc[i][j][r] + bv[j];
                    if (RELU) val = fmaxf(val, 0.f);
                    prow[j * 16] = f2h(val);
                }
            }
    }
}

// ---------------- softmax over f16 rows of 2048, in place ----------------
__global__ __launch_bounds__(256) void softmax_rows(u16* __restrict__ S) {
    const long row = blockIdx.x;
    u16* p = S + row * 2048;
    const int t = threadIdx.x;
    float v[8];
    float mx = -1e30f;
#pragma unroll
    for (int i = 0; i < 8; ++i) { v[i] = h2f(p[t + i * 256]); mx = fmaxf(mx, v[i]); }
    __shared__ float red[256];
    red[t] = mx; __syncthreads();
    for (int off = 128; off > 0; off >>= 1) {
        if (t < off) red[t] = fmaxf(red[t], red[t + off]);
        __syncthreads();
    }
    mx = red[0]; __syncthreads();
    float sum = 0.f;
#pragma unroll
    for (int i = 0; i < 8; ++i) { v[i] = __expf(v[i] - mx); sum += v[i]; }
    red[t] = sum; __syncthreads();
    for (int off = 128; off > 0; off >>= 1) {
        if (t < off) red[t] += red[t + off];
        __syncthreads();
    }
    const float inv = 1.f / red[0];
#pragma unroll
    for (int i = 0; i < 8; ++i) p[t + i * 256] = f2h(v[i] * inv);
}

// ---------------- ln1: xh_f16 = LN(src_f32 + attnO_f16) ----------------
__global__ __launch_bounds__(256) void ln_one(
    const float* __restrict__ a, const u16* __restrict__ bb,
    const float* __restrict__ g, const float* __restrict__ be,
    u16* __restrict__ out16)
{
    const long base = (long)blockIdx.x * 1024;
    const int t = threadIdx.x;
    float v[4]; float s = 0.f, ss = 0.f;
#pragma unroll
    for (int i = 0; i < 4; ++i) {
        const int c = t + i * 256;
        const float x = a[base + c] + h2f(bb[base + c]);
        v[i] = x; s += x; ss += x * x;
    }
    __shared__ float rs[256], rss[256];
    rs[t] = s; rss[t] = ss; __syncthreads();
    for (int off = 128; off > 0; off >>= 1) {
        if (t < off) { rs[t] += rs[t + off]; rss[t] += rss[t + off]; }
        __syncthreads();
    }
    const float mean = rs[0] * (1.f / 1024.f);
    const float var = rss[0] * (1.f / 1024.f) - mean * mean;
    const float rstd = rsqrtf(var + 1e-5f);
#pragma unroll
    for (int i = 0; i < 4; ++i) {
        const int c = t + i * 256;
        out16[base + c] = f2h((v[i] - mean) * rstd * g[c] + be[c]);
    }
}

// ---------------- ln2: out_f32 = LN(xh_f16 + ffO_f16) ----------------
__global__ __launch_bounds__(256) void ln_two(
    const u16* __restrict__ a, const u16* __restrict__ bb,
    const float* __restrict__ g, const float* __restrict__ be,
    float* __restrict__ out)
{
    const long base = (long)blockIdx.x * 1024;
    const int t = threadIdx.x;
    float v[4]; float s = 0.f, ss = 0.f;
#pragma unroll
    for (int i = 0; i < 4; ++i) {
        const int c = t + i * 256;
        const float x = h2f(a[base + c]) + h2f(bb[base + c]);
        v[i] = x; s += x; ss += x * x;
    }
    __shared__ float rs[256], rss[256];
    rs[t] = s; rss[t] = ss; __syncthreads();
    for (int off = 128; off > 0; off >>= 1) {
        if (t < off) { rs[t] += rs[t + off]; rss[t] += rss[t + off]; }
        __syncthreads();
    }
    const float mean = rs[0] * (1.f / 1024.f);
    const float var = rss[0] * (1.f / 1024.f) - mean * mean;
    const float rstd = rsqrtf(var + 1e-5f);
#pragma unroll
    for (int i = 0; i < 4; ++i) {
        const int c = t + i * 256;
        out[base + c] = (v[i] - mean) * rstd * g[c] + be[c];
    }
}

extern "C" void kernel_launch(void* const* d_in, const int* in_sizes, int n_in,
                              void* d_out, int out_size, void* d_ws, size_t ws_size,
                              hipStream_t stream) {
    (void)in_sizes; (void)n_in; (void)out_size; (void)ws_size;
    constexpr long S = 2048, E = 1024, F = 4096, M = 8192;

    const float* src = (const float*)d_in[0];
    const float* Wq  = (const float*)d_in[1];
    const float* bq  = (const float*)d_in[2];
    const float* Wk  = (const float*)d_in[3];
    const float* bk  = (const float*)d_in[4];
    const float* Wv  = (const float*)d_in[5];
    const float* bv  = (const float*)d_in[6];
    const float* Wo  = (const float*)d_in[7];
    const float* bo  = (const float*)d_in[8];
    const float* W1  = (const float*)d_in[9];
    const float* b1  = (const float*)d_in[10];
    const float* W2  = (const float*)d_in[11];
    const float* b2  = (const float*)d_in[12];
    const float* g1  = (const float*)d_in[13];
    const float* be1 = (const float*)d_in[14];
    const float* g2  = (const float*)d_in[15];
    const float* be2 = (const float*)d_in[16];

    char* ws = (char*)d_ws;
    size_t off = 0;
    auto take = [&](size_t bytes) {
        char* p = ws + off;
        off += (bytes + 255) & ~(size_t)255;
        return p;
    };
    const size_t MB16 = 16777216;  // f16 [8192][1024]
    u16*   srcH  = (u16*)take(MB16);
    u16*   WqkvT = (u16*)take(3 * E * E * 2);     // [3072][1024]: WqT | WkT | WvT
    u16*   WoT   = (u16*)take(E * E * 2);
    u16*   W1T   = (u16*)take(F * E * 2);         // [4096][1024]
    u16*   W2T   = (u16*)take(E * F * 2);         // [1024][4096]
    char*  B0    = take(2 * MB16);                // QK f16 [8192][2048]
    char*  B1    = take(MB16);                    // VT f16 [4][1024][2048]
    char*  B2    = take(4ull * S * S * 4);        // Sh f16 (32M) -> hf f16 [8192][4096] (64M)
    char*  B3    = take(MB16);                    // attn f16 -> xh f16
    char*  B4    = take(MB16);                    // attnO f16 -> ffO f16

    u16*   QK    = (u16*)B0;
    u16*   VT    = (u16*)B1;
    u16*   Sh    = (u16*)B2;
    u16*   hf    = (u16*)B2;
    u16*   attn  = (u16*)B3;
    u16*   xh    = (u16*)B3;
    u16*   attnO = (u16*)B4;
    u16*   ffO   = (u16*)B4;

    dim3 blk(256), blk5(512), tb(32, 8);

    // 1) convert src -> f16
    cvt_f16<<<dim3(M * E / 8 / 256), blk, 0, stream>>>(src, srcH, M * E / 8);

    // 2) all weight transposes in one launch
    transpose_all<<<dim3(12288), tb, 0, stream>>>(Wq, Wk, Wv, Wo, W1, W2,
                                                  WqkvT, WoT, W1T, W2T);

    // 3) merged Q|K|V projection: 768 blocks (2/CU resident)
    gemm256n<3, 3, false, 24, 32, 1><<<dim3(24 * 32), blk5, 0, stream>>>(
        srcH, E, 0, WqkvT, E, 0, QK, 2 * E, E * S, VT, bq, bk, bv, E);

    // 4) scores[b] = Q[b] @ K[b]^T: 512 blocks (2/CU resident)
    gemm256n<0, 0, false, 16, 8, 4><<<dim3(16 * 8 * 4), blk5, 0, stream>>>(
        QK, 2 * E, S * 2 * E, QK + E, 2 * E, S * 2 * E,
        Sh, S, S * S, nullptr, nullptr, nullptr, nullptr, E);

    // 5) softmax in place (f16)
    softmax_rows<<<dim3(M), blk, 0, stream>>>(Sh);

    // 6) attn[b] = P[b] @ V[b]: 256 blocks
    gemm256n<0, 0, false, 8, 8, 4><<<dim3(8 * 8 * 4), blk5, 0, stream>>>(
        Sh, S, S * S, VT, S, E * S,
        attn, E, S * E, nullptr, nullptr, nullptr, nullptr, S);

    // 7) attnO = attn @ Wo + bo: 256 blocks
    gemm256n<0, 1, false, 8, 32, 1><<<dim3(8 * 32), blk5, 0, stream>>>(
        attn, E, 0, WoT, E, 0, attnO, E, 0, nullptr, bo, nullptr, nullptr, E);

    // 8) xh = LN(src + attnO) (f16, over dead attn)
    ln_one<<<dim3(M), blk, 0, stream>>>(src, attnO, g1, be1, xh);

    // 9) hf = relu(xh @ W1 + b1): 1024 blocks (2/CU resident, 2 rounds)
    gemm256n<0, 1, true, 32, 32, 1><<<dim3(32 * 32), blk5, 0, stream>>>(
        xh, E, 0, W1T, E, 0, hf, F, 0, nullptr, b1, nullptr, nullptr, E);

    // 10) ffO = hf @ W2 + b2: 256 blocks, K=4096
    gemm256n<0, 1, false, 8, 32, 1><<<dim3(8 * 32), blk5, 0, stream>>>(
        hf, F, 0, W2T, F, 0, ffO, E, 0, nullptr, b2, nullptr, nullptr, F);

    // 11) out = LN(xh + ffO) -> f32
    ln_two<<<dim3(M), blk, 0, stream>>>(xh, ffO, g2, be2, (float*)d_out);
}